// Round 1
// baseline (1077.661 us; speedup 1.0000x reference)
//
#include <hip/hip_runtime.h>
#include <hip/hip_bf16.h>
#include <math.h>

#define BB 8
#define LL 2048
#define DMODEL 512
#define DINNER 1024
#define DSSM 512
#define NST 16
#define DTR 32

// ---------------------------------------------------------------------------
// Generic fp32 GEMM: C[M,N] = A[M,K] * W[N,K]^T   (both row-major, TN form)
// Tile: BM=64*GM x BN=64*GN, 256 threads, each thread computes (GM*4)x(GN*4).
// ---------------------------------------------------------------------------
template<int GM, int GN>
__global__ __launch_bounds__(256) void gemm_tn(const float* __restrict__ A,
    const float* __restrict__ W, float* __restrict__ C,
    int K, int lda, int ldw, int ldc) {
  constexpr int BM = 64 * GM, BN = 64 * GN;
  __shared__ float As[16][BM + 4];
  __shared__ float Ws[16][BN + 4];
  const int tid = threadIdx.x;
  const int tx = tid & 15, ty = tid >> 4;
  const long m0 = (long)blockIdx.y * BM, n0 = (long)blockIdx.x * BN;

  float acc[GM * 4][GN * 4];
#pragma unroll
  for (int i = 0; i < GM * 4; i++)
#pragma unroll
    for (int j = 0; j < GN * 4; j++) acc[i][j] = 0.f;

  for (int k0 = 0; k0 < K; k0 += 16) {
#pragma unroll
    for (int it = 0; it < GM; it++) {
      int idx = tid + it * 256;
      int row = idx >> 2, c4 = (idx & 3) << 2;
      float4 v = *(const float4*)(A + (m0 + row) * (long)lda + k0 + c4);
      As[c4 + 0][row] = v.x; As[c4 + 1][row] = v.y;
      As[c4 + 2][row] = v.z; As[c4 + 3][row] = v.w;
    }
#pragma unroll
    for (int it = 0; it < GN; it++) {
      int idx = tid + it * 256;
      int row = idx >> 2, c4 = (idx & 3) << 2;
      float4 v = *(const float4*)(W + (n0 + row) * (long)ldw + k0 + c4);
      Ws[c4 + 0][row] = v.x; Ws[c4 + 1][row] = v.y;
      Ws[c4 + 2][row] = v.z; Ws[c4 + 3][row] = v.w;
    }
    __syncthreads();
#pragma unroll
    for (int k = 0; k < 16; k++) {
      float a[GM * 4], bv[GN * 4];
#pragma unroll
      for (int g = 0; g < GM; g++) {
        float4 t4 = *(const float4*)&As[k][g * 64 + ty * 4];
        a[g * 4 + 0] = t4.x; a[g * 4 + 1] = t4.y;
        a[g * 4 + 2] = t4.z; a[g * 4 + 3] = t4.w;
      }
#pragma unroll
      for (int g = 0; g < GN; g++) {
        float4 t4 = *(const float4*)&Ws[k][g * 64 + tx * 4];
        bv[g * 4 + 0] = t4.x; bv[g * 4 + 1] = t4.y;
        bv[g * 4 + 2] = t4.z; bv[g * 4 + 3] = t4.w;
      }
#pragma unroll
      for (int i = 0; i < GM * 4; i++)
#pragma unroll
        for (int j = 0; j < GN * 4; j++)
          acc[i][j] += a[i] * bv[j];
    }
    __syncthreads();
  }

#pragma unroll
  for (int gm = 0; gm < GM; gm++)
#pragma unroll
    for (int i = 0; i < 4; i++) {
      long row = m0 + gm * 64 + ty * 4 + i;
#pragma unroll
      for (int gn = 0; gn < GN; gn++) {
        float4 o;
        o.x = acc[gm * 4 + i][gn * 4 + 0];
        o.y = acc[gm * 4 + i][gn * 4 + 1];
        o.z = acc[gm * 4 + i][gn * 4 + 2];
        o.w = acc[gm * 4 + i][gn * 4 + 3];
        *(float4*)(C + row * (long)ldc + n0 + gn * 64 + tx * 4) = o;
      }
    }
}

// ---------------------------------------------------------------------------
// Depthwise conv (width 4, pad (1,2)) + bias + SiLU for BOTH x and z halves.
// xz: (B, L, 1024). c<512 -> conv_x, write xc (B,L,512); c>=512 -> conv_z,
// write into ycat channel 512+(c-512) of (B,L,1024).
// ---------------------------------------------------------------------------
__global__ __launch_bounds__(256) void conv_silu_kernel(
    const float* __restrict__ xz,
    const float* __restrict__ cxw, const float* __restrict__ cxb,
    const float* __restrict__ czw, const float* __restrict__ czb,
    float* __restrict__ xc, float* __restrict__ ycat) {
  const int c = blockIdx.x * 256 + threadIdx.x;  // 0..1023
  const int l = blockIdx.y;
  const int b = blockIdx.z;
  const float* base = xz + ((size_t)b * LL) * DINNER + c;
  float w0, w1, w2, w3, bias;
  if (c < DSSM) {
    w0 = cxw[c * 4 + 0]; w1 = cxw[c * 4 + 1]; w2 = cxw[c * 4 + 2]; w3 = cxw[c * 4 + 3];
    bias = cxb[c];
  } else {
    int cz = c - DSSM;
    w0 = czw[cz * 4 + 0]; w1 = czw[cz * 4 + 1]; w2 = czw[cz * 4 + 2]; w3 = czw[cz * 4 + 3];
    bias = czb[cz];
  }
  float acc = bias;
  int li;
  li = l - 1; if (li >= 0)  acc += base[(size_t)li * DINNER] * w0;
  li = l;                   acc += base[(size_t)li * DINNER] * w1;
  li = l + 1; if (li < LL)  acc += base[(size_t)li * DINNER] * w2;
  li = l + 2; if (li < LL)  acc += base[(size_t)li * DINNER] * w3;
  float y = acc / (1.f + expf(-acc));  // SiLU
  if (c < DSSM)
    xc[((size_t)b * LL + l) * DSSM + c] = y;
  else
    ycat[((size_t)b * LL + l) * DINNER + c] = y;  // channels 512..1023
}

// ---------------------------------------------------------------------------
// dt = W_dt @ x_dbl[:,:32] ; delta = softplus(dt + b_dt) ;
// k2 = sum(k^2) ; eps = delta / (1 + delta*k2).  One block per (b,l).
// ---------------------------------------------------------------------------
__global__ __launch_bounds__(256) void dteps_kernel(
    const float* __restrict__ xdbl, const float* __restrict__ W_dt,
    const float* __restrict__ b_dt, float* __restrict__ eps) {
  const long bl = blockIdx.x;
  __shared__ float sd[64];
  __shared__ float sk2;
  const int t = threadIdx.x;
  if (t < 64) sd[t] = xdbl[bl * 64 + t];
  __syncthreads();
  if (t == 0) {
    float s = 0.f;
#pragma unroll
    for (int n = 0; n < NST; n++) { float kv = sd[32 + n]; s += kv * kv; }
    sk2 = s;
  }
  __syncthreads();
  const float k2 = sk2;
#pragma unroll
  for (int rep = 0; rep < 2; rep++) {
    const int d = t + rep * 256;
    float dt = b_dt[d];
    const float4* wr = (const float4*)&W_dt[d * DTR];
#pragma unroll
    for (int r4 = 0; r4 < 8; r4++) {
      float4 w = wr[r4];
      dt += w.x * sd[r4 * 4 + 0] + w.y * sd[r4 * 4 + 1] +
            w.z * sd[r4 * 4 + 2] + w.w * sd[r4 * 4 + 3];
    }
    float delta = (dt > 20.f) ? dt : log1pf(expf(dt));
    eps[bl * DSSM + d] = delta / (1.f + delta * k2);
  }
}

// ---------------------------------------------------------------------------
// Sequential scan over L. One thread per (b, d, n): S scalar recurrence
//   S += eps*(u - S*k)*k ;  y[d] = sum_n S*q[n]  (shfl reduce over 16 lanes)
// Block = 256 threads = 16 d x 16 n. Grid = (32 d-groups, 8 b).
// Register double-buffered prefetch of LCH timesteps.
// ---------------------------------------------------------------------------
#define LCH 8
__global__ __launch_bounds__(256) void scan_kernel(
    const float* __restrict__ eps, const float* __restrict__ xc,
    const float* __restrict__ xdbl, const float* __restrict__ D_skip,
    float* __restrict__ ycat) {
  const int b = blockIdx.y, dg = blockIdx.x;
  const int t = threadIdx.x, n = t & 15, dl = t >> 4;
  const int d = dg * NST + dl;
  const size_t bl0 = (size_t)b * LL;
  const float* ep = eps + bl0 * DSSM + d;
  const float* up = xc + bl0 * DSSM + d;
  const float* kp = xdbl + bl0 * 64 + 32 + n;  // q at +16
  float* yp = ycat + bl0 * DINNER + d;
  const float Dv = D_skip[d];
  float S = 0.f;

  float e0[LCH], u0[LCH], k0v[LCH], q0[LCH];
  float e1[LCH], u1[LCH], k1v[LCH], q1[LCH];
#pragma unroll
  for (int j = 0; j < LCH; j++) {
    e0[j] = ep[(size_t)j * DSSM];
    u0[j] = up[(size_t)j * DSSM];
    k0v[j] = kp[(size_t)j * 64];
    q0[j] = kp[(size_t)j * 64 + 16];
  }
  for (int l0 = 0; l0 < LL; l0 += 2 * LCH) {
    // prefetch bank1 (l0+LCH .. l0+2*LCH-1)  -- always in range
#pragma unroll
    for (int j = 0; j < LCH; j++) {
      const size_t l = l0 + LCH + j;
      e1[j] = ep[l * DSSM];
      u1[j] = up[l * DSSM];
      k1v[j] = kp[l * 64];
      q1[j] = kp[l * 64 + 16];
    }
    // compute bank0
#pragma unroll
    for (int j = 0; j < LCH; j++) {
      S += e0[j] * (u0[j] - S * k0v[j]) * k0v[j];
      float y = S * q0[j];
      y += __shfl_xor(y, 1); y += __shfl_xor(y, 2);
      y += __shfl_xor(y, 4); y += __shfl_xor(y, 8);
      if (n == 0) yp[(size_t)(l0 + j) * DINNER] = y + Dv * u0[j];
    }
    // prefetch bank0 for l0+2*LCH
    if (l0 + 2 * LCH < LL) {
#pragma unroll
      for (int j = 0; j < LCH; j++) {
        const size_t l = l0 + 2 * LCH + j;
        e0[j] = ep[l * DSSM];
        u0[j] = up[l * DSSM];
        k0v[j] = kp[l * 64];
        q0[j] = kp[l * 64 + 16];
      }
    }
    // compute bank1
#pragma unroll
    for (int j = 0; j < LCH; j++) {
      S += e1[j] * (u1[j] - S * k1v[j]) * k1v[j];
      float y = S * q1[j];
      y += __shfl_xor(y, 1); y += __shfl_xor(y, 2);
      y += __shfl_xor(y, 4); y += __shfl_xor(y, 8);
      if (n == 0) yp[(size_t)(l0 + LCH + j) * DINNER] = y + Dv * u1[j];
    }
  }
}

// ---------------------------------------------------------------------------
extern "C" void kernel_launch(void* const* d_in, const int* in_sizes, int n_in,
                              void* d_out, int out_size, void* d_ws, size_t ws_size,
                              hipStream_t stream) {
  const float* hidden  = (const float*)d_in[0];
  const float* W_in    = (const float*)d_in[1];
  const float* cxw     = (const float*)d_in[2];
  const float* cxb     = (const float*)d_in[3];
  const float* czw     = (const float*)d_in[4];
  const float* czb     = (const float*)d_in[5];
  const float* W_xproj = (const float*)d_in[6];
  const float* W_dt    = (const float*)d_in[7];
  const float* b_dt    = (const float*)d_in[8];
  const float* D_skip  = (const float*)d_in[9];
  const float* W_out   = (const float*)d_in[10];
  float* out = (float*)d_out;

  const size_t ML = (size_t)BB * LL;  // 16384
  float* xz   = (float*)d_ws;          // ML*1024
  float* xc   = xz + ML * DINNER;      // ML*512
  float* xdbl = xc + ML * DSSM;        // ML*64
  float* ycat = xdbl + ML * 64;        // ML*1024
  float* eps  = xz;                    // alias: xz dead after conv

  // 1) xz = hidden @ W_in^T   (16384x1024, K=512)
  gemm_tn<2, 2><<<dim3(DINNER / 128, ML / 128), 256, 0, stream>>>(
      hidden, W_in, xz, DMODEL, DMODEL, DMODEL, DINNER);

  // 2) depthwise conv + SiLU for both halves
  conv_silu_kernel<<<dim3(DINNER / 256, LL, BB), 256, 0, stream>>>(
      xz, cxw, cxb, czw, czb, xc, ycat);

  // 3) x_dbl = xc @ W_xproj^T  (16384x64, K=512)
  gemm_tn<2, 1><<<dim3(1, ML / 128), 256, 0, stream>>>(
      xc, W_xproj, xdbl, DSSM, DSSM, DSSM, 64);

  // 4) dt -> softplus -> eps
  dteps_kernel<<<dim3((unsigned)ML), 256, 0, stream>>>(xdbl, W_dt, b_dt, eps);

  // 5) sequential scan -> y (+ D_skip*u) into ycat channels 0..511
  scan_kernel<<<dim3(DSSM / NST, BB), 256, 0, stream>>>(
      eps, xc, xdbl, D_skip, ycat);

  // 6) out = ycat @ W_out^T  (16384x512, K=1024)
  gemm_tn<2, 2><<<dim3(DMODEL / 128, ML / 128), 256, 0, stream>>>(
      ycat, W_out, out, DINNER, DINNER, DINNER, DMODEL);
}

// Round 3
// 928.936 us; speedup vs baseline: 1.1601x; 1.1601x over previous
//
#include <hip/hip_runtime.h>
#include <hip/hip_bf16.h>
#include <math.h>

#define BB 8
#define LL 2048
#define DMODEL 512
#define DINNER 1024
#define DSSM 512
#define NST 16
#define DTR 32
#define CCH 16            // scan chunks
#define LC (LL / CCH)     // 128 steps per chunk
#define BDN (BB * DSSM * NST)  // 65536 scan lanes

// ---------------------------------------------------------------------------
// Generic fp32 GEMM: C[M,N] = A[M,K] * W[N,K]^T   (both row-major, TN form)
// ---------------------------------------------------------------------------
template<int GM, int GN>
__global__ __launch_bounds__(256) void gemm_tn(const float* __restrict__ A,
    const float* __restrict__ W, float* __restrict__ C,
    int K, int lda, int ldw, int ldc) {
  constexpr int BM = 64 * GM, BN = 64 * GN;
  __shared__ float As[16][BM + 4];
  __shared__ float Ws[16][BN + 4];
  const int tid = threadIdx.x;
  const int tx = tid & 15, ty = tid >> 4;
  const long m0 = (long)blockIdx.y * BM, n0 = (long)blockIdx.x * BN;

  float acc[GM * 4][GN * 4];
#pragma unroll
  for (int i = 0; i < GM * 4; i++)
#pragma unroll
    for (int j = 0; j < GN * 4; j++) acc[i][j] = 0.f;

  for (int k0 = 0; k0 < K; k0 += 16) {
#pragma unroll
    for (int it = 0; it < GM; it++) {
      int idx = tid + it * 256;
      int row = idx >> 2, c4 = (idx & 3) << 2;
      float4 v = *(const float4*)(A + (m0 + row) * (long)lda + k0 + c4);
      As[c4 + 0][row] = v.x; As[c4 + 1][row] = v.y;
      As[c4 + 2][row] = v.z; As[c4 + 3][row] = v.w;
    }
#pragma unroll
    for (int it = 0; it < GN; it++) {
      int idx = tid + it * 256;
      int row = idx >> 2, c4 = (idx & 3) << 2;
      float4 v = *(const float4*)(W + (n0 + row) * (long)ldw + k0 + c4);
      Ws[c4 + 0][row] = v.x; Ws[c4 + 1][row] = v.y;
      Ws[c4 + 2][row] = v.z; Ws[c4 + 3][row] = v.w;
    }
    __syncthreads();
#pragma unroll
    for (int k = 0; k < 16; k++) {
      float a[GM * 4], bv[GN * 4];
#pragma unroll
      for (int g = 0; g < GM; g++) {
        float4 t4 = *(const float4*)&As[k][g * 64 + ty * 4];
        a[g * 4 + 0] = t4.x; a[g * 4 + 1] = t4.y;
        a[g * 4 + 2] = t4.z; a[g * 4 + 3] = t4.w;
      }
#pragma unroll
      for (int g = 0; g < GN; g++) {
        float4 t4 = *(const float4*)&Ws[k][g * 64 + tx * 4];
        bv[g * 4 + 0] = t4.x; bv[g * 4 + 1] = t4.y;
        bv[g * 4 + 2] = t4.z; bv[g * 4 + 3] = t4.w;
      }
#pragma unroll
      for (int i = 0; i < GM * 4; i++)
#pragma unroll
        for (int j = 0; j < GN * 4; j++)
          acc[i][j] += a[i] * bv[j];
    }
    __syncthreads();
  }

#pragma unroll
  for (int gm = 0; gm < GM; gm++)
#pragma unroll
    for (int i = 0; i < 4; i++) {
      long row = m0 + gm * 64 + ty * 4 + i;
#pragma unroll
      for (int gn = 0; gn < GN; gn++) {
        float4 o;
        o.x = acc[gm * 4 + i][gn * 4 + 0];
        o.y = acc[gm * 4 + i][gn * 4 + 1];
        o.z = acc[gm * 4 + i][gn * 4 + 2];
        o.w = acc[gm * 4 + i][gn * 4 + 3];
        *(float4*)(C + row * (long)ldc + n0 + gn * 64 + tx * 4) = o;
      }
    }
}

// ---------------------------------------------------------------------------
// Depthwise conv (width 4, pad (1,2)) + bias + SiLU for BOTH x and z halves.
// ---------------------------------------------------------------------------
__global__ __launch_bounds__(256) void conv_silu_kernel(
    const float* __restrict__ xz,
    const float* __restrict__ cxw, const float* __restrict__ cxb,
    const float* __restrict__ czw, const float* __restrict__ czb,
    float* __restrict__ xc, float* __restrict__ ycat) {
  const int c = blockIdx.x * 256 + threadIdx.x;  // 0..1023
  const int l = blockIdx.y;
  const int b = blockIdx.z;
  const float* base = xz + ((size_t)b * LL) * DINNER + c;
  float w0, w1, w2, w3, bias;
  if (c < DSSM) {
    w0 = cxw[c * 4 + 0]; w1 = cxw[c * 4 + 1]; w2 = cxw[c * 4 + 2]; w3 = cxw[c * 4 + 3];
    bias = cxb[c];
  } else {
    int cz = c - DSSM;
    w0 = czw[cz * 4 + 0]; w1 = czw[cz * 4 + 1]; w2 = czw[cz * 4 + 2]; w3 = czw[cz * 4 + 3];
    bias = czb[cz];
  }
  float acc = bias;
  int li;
  li = l - 1; if (li >= 0)  acc += base[(size_t)li * DINNER] * w0;
  li = l;                   acc += base[(size_t)li * DINNER] * w1;
  li = l + 1; if (li < LL)  acc += base[(size_t)li * DINNER] * w2;
  li = l + 2; if (li < LL)  acc += base[(size_t)li * DINNER] * w3;
  float y = acc / (1.f + expf(-acc));  // SiLU
  if (c < DSSM)
    xc[((size_t)b * LL + l) * DSSM + c] = y;
  else
    ycat[((size_t)b * LL + l) * DINNER + c] = y;  // channels 512..1023
}

// ---------------------------------------------------------------------------
// dt = W_dt @ x_dbl[:,:32] ; delta = softplus(dt + b_dt) ;
// k2 = sum(k^2) ; eps = delta / (1 + delta*k2).  One block per (b,l).
// ---------------------------------------------------------------------------
__global__ __launch_bounds__(256) void dteps_kernel(
    const float* __restrict__ xdbl, const float* __restrict__ W_dt,
    const float* __restrict__ b_dt, float* __restrict__ eps) {
  const long bl = blockIdx.x;
  __shared__ float sd[64];
  __shared__ float sk2;
  const int t = threadIdx.x;
  if (t < 64) sd[t] = xdbl[bl * 64 + t];
  __syncthreads();
  if (t == 0) {
    float s = 0.f;
#pragma unroll
    for (int n = 0; n < NST; n++) { float kv = sd[32 + n]; s += kv * kv; }
    sk2 = s;
  }
  __syncthreads();
  const float k2 = sk2;
#pragma unroll
  for (int rep = 0; rep < 2; rep++) {
    const int d = t + rep * 256;
    float dt = b_dt[d];
    const float4* wr = (const float4*)&W_dt[d * DTR];
#pragma unroll
    for (int r4 = 0; r4 < 8; r4++) {
      float4 w = wr[r4];
      dt += w.x * sd[r4 * 4 + 0] + w.y * sd[r4 * 4 + 1] +
            w.z * sd[r4 * 4 + 2] + w.w * sd[r4 * 4 + 3];
    }
    float delta = (dt > 20.f) ? dt : log1pf(expf(dt));
    eps[bl * DSSM + d] = delta / (1.f + delta * k2);
  }
}

// ---------------------------------------------------------------------------
// Chunked scan. Recurrence S_t = a_t*S_{t-1} + b_t with
//   a = 1 - eps*k^2, b = eps*u*k.
// Pass A: per chunk (128 steps) compute A = prod a, B = chunk-local end state
// (start 0). Grid (32 dgroups, 8 b, 16 chunks) = 4096 blocks -> full TLP.
// Pass C: prefix-combine (A,B) of previous chunks to get start state, then
// recompute chunk emitting y = sum_n S*q[n] + D*u.
// ---------------------------------------------------------------------------
__global__ __launch_bounds__(256) void scan_passA(
    const float* __restrict__ eps, const float* __restrict__ xc,
    const float* __restrict__ xdbl,
    float* __restrict__ Ach, float* __restrict__ Bch) {
  const int dg = blockIdx.x, b = blockIdx.y, ch = blockIdx.z;
  const int t = threadIdx.x, n = t & 15, dl = t >> 4;
  const int d = dg * NST + dl;
  const size_t bl0 = (size_t)b * LL + (size_t)ch * LC;
  const float* ep = eps + bl0 * DSSM + d;
  const float* up = xc + bl0 * DSSM + d;
  const float* kp = xdbl + bl0 * 64 + 32 + n;
  float A = 1.f, S = 0.f;
#pragma unroll 8
  for (int j = 0; j < LC; j++) {
    float e = ep[(size_t)j * DSSM];
    float u = up[(size_t)j * DSSM];
    float k = kp[(size_t)j * 64];
    float t0 = e * k;
    float a = fmaf(-t0, k, 1.f);
    A *= a;
    S = fmaf(S, a, t0 * u);
  }
  const size_t bdn = (((size_t)b * DSSM + d) * NST) + n;
  Ach[(size_t)ch * BDN + bdn] = A;
  Bch[(size_t)ch * BDN + bdn] = S;
}

__global__ __launch_bounds__(256) void scan_passC(
    const float* __restrict__ eps, const float* __restrict__ xc,
    const float* __restrict__ xdbl, const float* __restrict__ D_skip,
    const float* __restrict__ Ach, const float* __restrict__ Bch,
    float* __restrict__ ycat) {
  const int dg = blockIdx.x, b = blockIdx.y, ch = blockIdx.z;
  const int t = threadIdx.x, n = t & 15, dl = t >> 4;
  const int d = dg * NST + dl;
  const size_t bdn = (((size_t)b * DSSM + d) * NST) + n;

  // prefix combine over previous chunks (<=15 dependent FMAs)
  float S = 0.f;
  for (int c = 0; c < ch; c++) {
    float Av = Ach[(size_t)c * BDN + bdn];
    float Bv = Bch[(size_t)c * BDN + bdn];
    S = fmaf(S, Av, Bv);
  }

  const size_t bl0 = (size_t)b * LL + (size_t)ch * LC;
  const float* ep = eps + bl0 * DSSM + d;
  const float* up = xc + bl0 * DSSM + d;
  const float* kp = xdbl + bl0 * 64 + 32 + n;  // q at +16
  float* yp = ycat + bl0 * DINNER + d;
  const float Dv = D_skip[d];

#pragma unroll 4
  for (int j = 0; j < LC; j++) {
    float e = ep[(size_t)j * DSSM];
    float u = up[(size_t)j * DSSM];
    float k = kp[(size_t)j * 64];
    float q = kp[(size_t)j * 64 + 16];
    float t0 = e * k;
    float a = fmaf(-t0, k, 1.f);
    S = fmaf(S, a, t0 * u);
    float y = S * q;
    y += __shfl_xor(y, 1); y += __shfl_xor(y, 2);
    y += __shfl_xor(y, 4); y += __shfl_xor(y, 8);
    if (n == 0) yp[(size_t)j * DINNER] = fmaf(Dv, u, y);
  }
}

// ---------------------------------------------------------------------------
extern "C" void kernel_launch(void* const* d_in, const int* in_sizes, int n_in,
                              void* d_out, int out_size, void* d_ws, size_t ws_size,
                              hipStream_t stream) {
  const float* hidden  = (const float*)d_in[0];
  const float* W_in    = (const float*)d_in[1];
  const float* cxw     = (const float*)d_in[2];
  const float* cxb     = (const float*)d_in[3];
  const float* czw     = (const float*)d_in[4];
  const float* czb     = (const float*)d_in[5];
  const float* W_xproj = (const float*)d_in[6];
  const float* W_dt    = (const float*)d_in[7];
  const float* b_dt    = (const float*)d_in[8];
  const float* D_skip  = (const float*)d_in[9];
  const float* W_out   = (const float*)d_in[10];
  float* out = (float*)d_out;

  const size_t ML = (size_t)BB * LL;  // 16384
  float* xz   = (float*)d_ws;          // ML*1024 floats
  float* xc   = xz + ML * DINNER;      // ML*512
  float* xdbl = xc + ML * DSSM;        // ML*64
  float* ycat = xdbl + ML * 64;        // ML*1024
  float* eps  = xz;                    // alias: first ML*512 of xz (dead after conv)
  float* Ach  = xz + ML * DSSM;        // alias: second half of xz region (1M floats)
  float* Bch  = Ach + (size_t)CCH * BDN;  // +1M floats (fits: 2*CCH*BDN = 2M < ML*512 = 8.4M)

  // 1) xz = hidden @ W_in^T   (16384x1024, K=512)
  gemm_tn<2, 2><<<dim3(DINNER / 128, ML / 128), 256, 0, stream>>>(
      hidden, W_in, xz, DMODEL, DMODEL, DMODEL, DINNER);

  // 2) depthwise conv + SiLU for both halves
  conv_silu_kernel<<<dim3(DINNER / 256, LL, BB), 256, 0, stream>>>(
      xz, cxw, cxb, czw, czb, xc, ycat);

  // 3) x_dbl = xc @ W_xproj^T  (16384x64, K=512)
  gemm_tn<2, 1><<<dim3(1, ML / 128), 256, 0, stream>>>(
      xc, W_xproj, xdbl, DSSM, DSSM, DSSM, 64);

  // 4) dt -> softplus -> eps  (eps overwrites xz[0:ML*512], xz now dead)
  dteps_kernel<<<dim3((unsigned)ML), 256, 0, stream>>>(xdbl, W_dt, b_dt, eps);

  // 5) chunked scan -> y into ycat channels 0..511
  scan_passA<<<dim3(DSSM / NST, BB, CCH), 256, 0, stream>>>(
      eps, xc, xdbl, Ach, Bch);
  scan_passC<<<dim3(DSSM / NST, BB, CCH), 256, 0, stream>>>(
      eps, xc, xdbl, D_skip, Ach, Bch, ycat);

  // 6) out = ycat @ W_out^T  (16384x512, K=1024)
  gemm_tn<2, 2><<<dim3(DMODEL / 128, ML / 128), 256, 0, stream>>>(
      ycat, W_out, out, DINNER, DINNER, DINNER, DMODEL);
}

// Round 4
// 648.713 us; speedup vs baseline: 1.6612x; 1.4320x over previous
//
#include <hip/hip_runtime.h>
#include <hip/hip_bf16.h>
#include <math.h>

#define BB 8
#define LL 2048
#define DMODEL 512
#define DINNER 1024
#define DSSM 512
#define NST 16
#define DTR 32
#define CCH 16            // scan chunks
#define LC (LL / CCH)     // 128 steps per chunk
#define BDN (BB * DSSM * NST)  // 65536 scan lanes

typedef short short8 __attribute__((ext_vector_type(8)));
typedef float f32x4 __attribute__((ext_vector_type(4)));

// ---- bf16 helpers (RNE, bit-level; avoids __hip_bfloat16 ABI deps) --------
__device__ __forceinline__ unsigned short f2bf(float f) {
  unsigned u = __float_as_uint(f);
  u += 0x7FFFu + ((u >> 16) & 1u);
  return (unsigned short)(u >> 16);
}
__device__ __forceinline__ float bf2f(unsigned short s) {
  return __uint_as_float(((unsigned)s) << 16);
}

__device__ __forceinline__ void gload16(const void* g, void* l) {
  __builtin_amdgcn_global_load_lds(
      (const __attribute__((address_space(1))) void*)g,
      (__attribute__((address_space(3))) void*)l, 16, 0, 0);
}

// ---------------------------------------------------------------------------
// split-bf16 MFMA GEMM: C[M,N](fp32) = (Ahi+Alo)[M,K] * (Whi+Wlo)[N,K]^T
// A planes: Ab (hi), Ab+planeA (lo), row-major [M][K] bf16 bits. Same for W.
// 128x128 tile, BK=32, 256 thr (4 waves, 2x2 of 64x64). LDS rows = 128B:
// [hi k0..31 | lo k0..31], granule-XOR-swizzled: phys slot s holds logical
// g = s ^ (row&7) (applied on gload source AND ds_read addr).
// 3 MFMAs per (m,n): hi*hi + hi*lo + lo*hi  (drops lo*lo ~ 2^-16 rel).
// ---------------------------------------------------------------------------
__global__ __launch_bounds__(256) void gemm_mfma_split(
    const unsigned short* __restrict__ Ab, size_t planeA,
    const unsigned short* __restrict__ Wb, size_t planeW,
    float* __restrict__ Cout, int K, int NBN) {
  __shared__ unsigned short tA[128 * 64];
  __shared__ unsigned short tW[128 * 64];
  const int tid = threadIdx.x;
  const int ln = tid & 63;
  const int wv = tid >> 6;
  const int wr = wv >> 1, wc = wv & 1;
  const int lr = ln & 15, kc = ln >> 4;

  // XCD-chunked block swizzle (nwg % 8 == 0), M-major wg order:
  // each XCD gets a contiguous M-range x all N (W is tiny, A read ~once).
  const int nwg = gridDim.x;
  const int q = nwg >> 3;
  const int bid = blockIdx.x;
  const int wg = (bid & 7) * q + (bid >> 3);
  const int mblk = wg / NBN, nblk = wg % NBN;
  const size_t m0 = (size_t)mblk * 128, n0 = (size_t)nblk * 128;

  f32x4 acc[4][4];
#pragma unroll
  for (int m = 0; m < 4; ++m)
#pragma unroll
    for (int n = 0; n < 4; ++n)
#pragma unroll
      for (int j = 0; j < 4; ++j) acc[m][n][j] = 0.f;

  const int wbase = (tid & 0xC0) << 4;  // wave-uniform byte base

  for (int k0 = 0; k0 < K; k0 += 32) {
#pragma unroll
    for (int it = 0; it < 4; ++it) {
      const int gi = it * 256 + tid;
      const int r = gi >> 3, s = gi & 7, g = s ^ (r & 7);
      const size_t off = (size_t)(g >> 2) * planeA + (m0 + r) * (size_t)K
                       + (size_t)(k0 + (g & 3) * 8);
      gload16(Ab + off, (char*)tA + it * 4096 + wbase);
    }
#pragma unroll
    for (int it = 0; it < 4; ++it) {
      const int gi = it * 256 + tid;
      const int r = gi >> 3, s = gi & 7, g = s ^ (r & 7);
      const size_t off = (size_t)(g >> 2) * planeW + (n0 + r) * (size_t)K
                       + (size_t)(k0 + (g & 3) * 8);
      gload16(Wb + off, (char*)tW + it * 4096 + wbase);
    }
    __syncthreads();

    short8 ah[4], al[4], wh[4], wl[4];
#pragma unroll
    for (int m = 0; m < 4; ++m) {
      const int ra = wr * 64 + m * 16 + lr;
      const int hs = kc ^ (ra & 7);
      const char* base = (const char*)tA + ra * 128;
      ah[m] = *(const short8*)(base + hs * 16);
      al[m] = *(const short8*)(base + (hs ^ 4) * 16);
    }
#pragma unroll
    for (int n = 0; n < 4; ++n) {
      const int rb = wc * 64 + n * 16 + lr;
      const int hs = kc ^ (rb & 7);
      const char* base = (const char*)tW + rb * 128;
      wh[n] = *(const short8*)(base + hs * 16);
      wl[n] = *(const short8*)(base + (hs ^ 4) * 16);
    }
#pragma unroll
    for (int m = 0; m < 4; ++m)
#pragma unroll
      for (int n = 0; n < 4; ++n) {
        acc[m][n] = __builtin_amdgcn_mfma_f32_16x16x32_bf16(ah[m], wh[n], acc[m][n], 0, 0, 0);
        acc[m][n] = __builtin_amdgcn_mfma_f32_16x16x32_bf16(ah[m], wl[n], acc[m][n], 0, 0, 0);
        acc[m][n] = __builtin_amdgcn_mfma_f32_16x16x32_bf16(al[m], wh[n], acc[m][n], 0, 0, 0);
      }
    __syncthreads();
  }

  // C/D layout (verified): col = lane&15, row = (lane>>4)*4 + reg
  const int ldc = NBN * 128;
#pragma unroll
  for (int m = 0; m < 4; ++m) {
    const size_t row0 = m0 + wr * 64 + m * 16 + kc * 4;
#pragma unroll
    for (int n = 0; n < 4; ++n) {
      const size_t col = n0 + wc * 64 + n * 16 + lr;
#pragma unroll
      for (int j = 0; j < 4; ++j)
        Cout[(row0 + j) * (size_t)ldc + col] = acc[m][n][j];
    }
  }
}

// ---------------------------------------------------------------------------
// fp32 -> (hi, lo) bf16 planes. n4 = n/4.
// ---------------------------------------------------------------------------
__global__ __launch_bounds__(256) void split_kernel(const float* __restrict__ in,
    unsigned short* __restrict__ hi, unsigned short* __restrict__ lo, int n4) {
  int i = blockIdx.x * 256 + threadIdx.x;
  const int str = gridDim.x * 256;
  for (; i < n4; i += str) {
    const float4 v = ((const float4*)in)[i];
    ushort4 h, l;
    h.x = f2bf(v.x); l.x = f2bf(v.x - bf2f(h.x));
    h.y = f2bf(v.y); l.y = f2bf(v.y - bf2f(h.y));
    h.z = f2bf(v.z); l.z = f2bf(v.z - bf2f(h.z));
    h.w = f2bf(v.w); l.w = f2bf(v.w - bf2f(h.w));
    ((ushort4*)hi)[i] = h;
    ((ushort4*)lo)[i] = l;
  }
}

// ---------------------------------------------------------------------------
// Generic fp32 GEMM (kept for the small x_dbl projection, N=64).
// ---------------------------------------------------------------------------
template<int GM, int GN>
__global__ __launch_bounds__(256) void gemm_tn(const float* __restrict__ A,
    const float* __restrict__ W, float* __restrict__ C,
    int K, int lda, int ldw, int ldc) {
  constexpr int BM = 64 * GM, BN = 64 * GN;
  __shared__ float As[16][BM + 4];
  __shared__ float Ws[16][BN + 4];
  const int tid = threadIdx.x;
  const int tx = tid & 15, ty = tid >> 4;
  const long m0 = (long)blockIdx.y * BM, n0 = (long)blockIdx.x * BN;

  float acc[GM * 4][GN * 4];
#pragma unroll
  for (int i = 0; i < GM * 4; i++)
#pragma unroll
    for (int j = 0; j < GN * 4; j++) acc[i][j] = 0.f;

  for (int k0 = 0; k0 < K; k0 += 16) {
#pragma unroll
    for (int it = 0; it < GM; it++) {
      int idx = tid + it * 256;
      int row = idx >> 2, c4 = (idx & 3) << 2;
      float4 v = *(const float4*)(A + (m0 + row) * (long)lda + k0 + c4);
      As[c4 + 0][row] = v.x; As[c4 + 1][row] = v.y;
      As[c4 + 2][row] = v.z; As[c4 + 3][row] = v.w;
    }
#pragma unroll
    for (int it = 0; it < GN; it++) {
      int idx = tid + it * 256;
      int row = idx >> 2, c4 = (idx & 3) << 2;
      float4 v = *(const float4*)(W + (n0 + row) * (long)ldw + k0 + c4);
      Ws[c4 + 0][row] = v.x; Ws[c4 + 1][row] = v.y;
      Ws[c4 + 2][row] = v.z; Ws[c4 + 3][row] = v.w;
    }
    __syncthreads();
#pragma unroll
    for (int k = 0; k < 16; k++) {
      float a[GM * 4], bv[GN * 4];
#pragma unroll
      for (int g = 0; g < GM; g++) {
        float4 t4 = *(const float4*)&As[k][g * 64 + ty * 4];
        a[g * 4 + 0] = t4.x; a[g * 4 + 1] = t4.y;
        a[g * 4 + 2] = t4.z; a[g * 4 + 3] = t4.w;
      }
#pragma unroll
      for (int g = 0; g < GN; g++) {
        float4 t4 = *(const float4*)&Ws[k][g * 64 + tx * 4];
        bv[g * 4 + 0] = t4.x; bv[g * 4 + 1] = t4.y;
        bv[g * 4 + 2] = t4.z; bv[g * 4 + 3] = t4.w;
      }
#pragma unroll
      for (int i = 0; i < GM * 4; i++)
#pragma unroll
        for (int j = 0; j < GN * 4; j++)
          acc[i][j] += a[i] * bv[j];
    }
    __syncthreads();
  }

#pragma unroll
  for (int gm = 0; gm < GM; gm++)
#pragma unroll
    for (int i = 0; i < 4; i++) {
      long row = m0 + gm * 64 + ty * 4 + i;
#pragma unroll
      for (int gn = 0; gn < GN; gn++) {
        float4 o;
        o.x = acc[gm * 4 + i][gn * 4 + 0];
        o.y = acc[gm * 4 + i][gn * 4 + 1];
        o.z = acc[gm * 4 + i][gn * 4 + 2];
        o.w = acc[gm * 4 + i][gn * 4 + 3];
        *(float4*)(C + row * (long)ldc + n0 + gn * 64 + tx * 4) = o;
      }
    }
}

// ---------------------------------------------------------------------------
// Depthwise conv + bias + SiLU. x-half -> xc (fp32); z-half -> y hi/lo planes.
// ---------------------------------------------------------------------------
__global__ __launch_bounds__(256) void conv_silu_kernel(
    const float* __restrict__ xz,
    const float* __restrict__ cxw, const float* __restrict__ cxb,
    const float* __restrict__ czw, const float* __restrict__ czb,
    float* __restrict__ xc,
    unsigned short* __restrict__ yHi, unsigned short* __restrict__ yLo) {
  const int c = blockIdx.x * 256 + threadIdx.x;  // 0..1023
  const int l = blockIdx.y;
  const int b = blockIdx.z;
  const float* base = xz + ((size_t)b * LL) * DINNER + c;
  float w0, w1, w2, w3, bias;
  if (c < DSSM) {
    w0 = cxw[c * 4 + 0]; w1 = cxw[c * 4 + 1]; w2 = cxw[c * 4 + 2]; w3 = cxw[c * 4 + 3];
    bias = cxb[c];
  } else {
    int cz = c - DSSM;
    w0 = czw[cz * 4 + 0]; w1 = czw[cz * 4 + 1]; w2 = czw[cz * 4 + 2]; w3 = czw[cz * 4 + 3];
    bias = czb[cz];
  }
  float acc = bias;
  int li;
  li = l - 1; if (li >= 0)  acc += base[(size_t)li * DINNER] * w0;
  li = l;                   acc += base[(size_t)li * DINNER] * w1;
  li = l + 1; if (li < LL)  acc += base[(size_t)li * DINNER] * w2;
  li = l + 2; if (li < LL)  acc += base[(size_t)li * DINNER] * w3;
  float y = acc / (1.f + expf(-acc));  // SiLU
  if (c < DSSM) {
    xc[((size_t)b * LL + l) * DSSM + c] = y;
  } else {
    const size_t idx = ((size_t)b * LL + l) * DINNER + c;
    unsigned short h = f2bf(y);
    yHi[idx] = h;
    yLo[idx] = f2bf(y - bf2f(h));
  }
}

// ---------------------------------------------------------------------------
// dt = W_dt @ x_dbl[:,:32] ; delta = softplus(dt + b_dt) ;
// k2 = sum(k^2) ; eps = delta / (1 + delta*k2).  One block per (b,l).
// ---------------------------------------------------------------------------
__global__ __launch_bounds__(256) void dteps_kernel(
    const float* __restrict__ xdbl, const float* __restrict__ W_dt,
    const float* __restrict__ b_dt, float* __restrict__ eps) {
  const long bl = blockIdx.x;
  __shared__ float sd[64];
  __shared__ float sk2;
  const int t = threadIdx.x;
  if (t < 64) sd[t] = xdbl[bl * 64 + t];
  __syncthreads();
  if (t == 0) {
    float s = 0.f;
#pragma unroll
    for (int n = 0; n < NST; n++) { float kv = sd[32 + n]; s += kv * kv; }
    sk2 = s;
  }
  __syncthreads();
  const float k2 = sk2;
#pragma unroll
  for (int rep = 0; rep < 2; rep++) {
    const int d = t + rep * 256;
    float dt = b_dt[d];
    const float4* wr = (const float4*)&W_dt[d * DTR];
#pragma unroll
    for (int r4 = 0; r4 < 8; r4++) {
      float4 w = wr[r4];
      dt += w.x * sd[r4 * 4 + 0] + w.y * sd[r4 * 4 + 1] +
            w.z * sd[r4 * 4 + 2] + w.w * sd[r4 * 4 + 3];
    }
    float delta = (dt > 20.f) ? dt : log1pf(expf(dt));
    eps[bl * DSSM + d] = delta / (1.f + delta * k2);
  }
}

// ---------------------------------------------------------------------------
// Chunked scan (S_t = a_t*S_{t-1} + b_t; a = 1-eps*k^2, b = eps*u*k).
// ---------------------------------------------------------------------------
__global__ __launch_bounds__(256) void scan_passA(
    const float* __restrict__ eps, const float* __restrict__ xc,
    const float* __restrict__ xdbl,
    float* __restrict__ Ach, float* __restrict__ Bch) {
  const int dg = blockIdx.x, b = blockIdx.y, ch = blockIdx.z;
  const int t = threadIdx.x, n = t & 15, dl = t >> 4;
  const int d = dg * NST + dl;
  const size_t bl0 = (size_t)b * LL + (size_t)ch * LC;
  const float* ep = eps + bl0 * DSSM + d;
  const float* up = xc + bl0 * DSSM + d;
  const float* kp = xdbl + bl0 * 64 + 32 + n;
  float A = 1.f, S = 0.f;
#pragma unroll 8
  for (int j = 0; j < LC; j++) {
    float e = ep[(size_t)j * DSSM];
    float u = up[(size_t)j * DSSM];
    float k = kp[(size_t)j * 64];
    float t0 = e * k;
    float a = fmaf(-t0, k, 1.f);
    A *= a;
    S = fmaf(S, a, t0 * u);
  }
  const size_t bdn = (((size_t)b * DSSM + d) * NST) + n;
  Ach[(size_t)ch * BDN + bdn] = A;
  Bch[(size_t)ch * BDN + bdn] = S;
}

__global__ __launch_bounds__(256) void scan_passC(
    const float* __restrict__ eps, const float* __restrict__ xc,
    const float* __restrict__ xdbl, const float* __restrict__ D_skip,
    const float* __restrict__ Ach, const float* __restrict__ Bch,
    unsigned short* __restrict__ yHi, unsigned short* __restrict__ yLo) {
  const int dg = blockIdx.x, b = blockIdx.y, ch = blockIdx.z;
  const int t = threadIdx.x, n = t & 15, dl = t >> 4;
  const int d = dg * NST + dl;
  const size_t bdn = (((size_t)b * DSSM + d) * NST) + n;

  float S = 0.f;
  for (int c = 0; c < ch; c++) {
    float Av = Ach[(size_t)c * BDN + bdn];
    float Bv = Bch[(size_t)c * BDN + bdn];
    S = fmaf(S, Av, Bv);
  }

  const size_t bl0 = (size_t)b * LL + (size_t)ch * LC;
  const float* ep = eps + bl0 * DSSM + d;
  const float* up = xc + bl0 * DSSM + d;
  const float* kp = xdbl + bl0 * 64 + 32 + n;  // q at +16
  unsigned short* ypH = yHi + bl0 * DINNER + d;
  unsigned short* ypL = yLo + bl0 * DINNER + d;
  const float Dv = D_skip[d];

#pragma unroll 4
  for (int j = 0; j < LC; j++) {
    float e = ep[(size_t)j * DSSM];
    float u = up[(size_t)j * DSSM];
    float k = kp[(size_t)j * 64];
    float q = kp[(size_t)j * 64 + 16];
    float t0 = e * k;
    float a = fmaf(-t0, k, 1.f);
    S = fmaf(S, a, t0 * u);
    float y = S * q;
    y += __shfl_xor(y, 1); y += __shfl_xor(y, 2);
    y += __shfl_xor(y, 4); y += __shfl_xor(y, 8);
    if (n == 0) {
      float yv = fmaf(Dv, u, y);
      unsigned short h = f2bf(yv);
      ypH[(size_t)j * DINNER] = h;
      ypL[(size_t)j * DINNER] = f2bf(yv - bf2f(h));
    }
  }
}

// ---------------------------------------------------------------------------
extern "C" void kernel_launch(void* const* d_in, const int* in_sizes, int n_in,
                              void* d_out, int out_size, void* d_ws, size_t ws_size,
                              hipStream_t stream) {
  const float* hidden  = (const float*)d_in[0];
  const float* W_in    = (const float*)d_in[1];
  const float* cxw     = (const float*)d_in[2];
  const float* cxb     = (const float*)d_in[3];
  const float* czw     = (const float*)d_in[4];
  const float* czb     = (const float*)d_in[5];
  const float* W_xproj = (const float*)d_in[6];
  const float* W_dt    = (const float*)d_in[7];
  const float* b_dt    = (const float*)d_in[8];
  const float* D_skip  = (const float*)d_in[9];
  const float* W_out   = (const float*)d_in[10];
  float* out = (float*)d_out;

  const size_t ML  = (size_t)BB * LL;      // 16384
  const size_t MK5 = ML * DSSM;            // 8.4M  (hidden plane elems)
  const size_t MN  = ML * DINNER;          // 16.8M (y plane elems)
  const size_t WIN = (size_t)DINNER * DMODEL;  // 0.52M
  const size_t WOU = (size_t)DMODEL * DINNER;  // 0.52M

  unsigned short* hidS  = (unsigned short*)d_ws;   // 2*MK5 shorts
  unsigned short* WinS  = hidS + 2 * MK5;          // 2*WIN shorts
  unsigned short* WoutS = WinS + 2 * WIN;          // 2*WOU shorts
  float* xz   = (float*)(WoutS + 2 * WOU);         // MN floats
  float* xc   = xz + MN;                           // MK5 floats
  float* xdbl = xc + MK5;                          // ML*64 floats
  unsigned short* yS = (unsigned short*)(xdbl + ML * 64);  // 2*MN shorts
  float* eps = xz;                                 // alias: xz dead after conv
  float* Ach = (float*)hidS;                       // alias: hidS dead after GEMM1
  float* Bch = Ach + (size_t)CCH * BDN;

  // 0) fp32 -> split-bf16 planes
  split_kernel<<<2048, 256, 0, stream>>>(hidden, hidS, hidS + MK5, (int)(MK5 / 4));
  split_kernel<<<512, 256, 0, stream>>>(W_in, WinS, WinS + WIN, (int)(WIN / 4));
  split_kernel<<<512, 256, 0, stream>>>(W_out, WoutS, WoutS + WOU, (int)(WOU / 4));

  // 1) xz = hidden @ W_in^T   (MFMA split-bf16; M=16384, N=1024, K=512)
  gemm_mfma_split<<<(16384 / 128) * (1024 / 128), 256, 0, stream>>>(
      hidS, MK5, WinS, WIN, xz, DMODEL, DINNER / 128);

  // 2) depthwise conv + SiLU
  conv_silu_kernel<<<dim3(DINNER / 256, LL, BB), 256, 0, stream>>>(
      xz, cxw, cxb, czw, czb, xc, yS, yS + MN);

  // 3) x_dbl = xc @ W_xproj^T  (fp32, N=64)
  gemm_tn<2, 1><<<dim3(1, ML / 128), 256, 0, stream>>>(
      xc, W_xproj, xdbl, DSSM, DSSM, DSSM, 64);

  // 4) dt -> softplus -> eps
  dteps_kernel<<<dim3((unsigned)ML), 256, 0, stream>>>(xdbl, W_dt, b_dt, eps);

  // 5) chunked scan -> y (split planes, cols 0..511)
  scan_passA<<<dim3(DSSM / NST, BB, CCH), 256, 0, stream>>>(
      eps, xc, xdbl, Ach, Bch);
  scan_passC<<<dim3(DSSM / NST, BB, CCH), 256, 0, stream>>>(
      eps, xc, xdbl, D_skip, Ach, Bch, yS, yS + MN);

  // 6) out = ycat @ W_out^T  (MFMA split-bf16; M=16384, N=512, K=1024)
  gemm_mfma_split<<<(16384 / 128) * (512 / 128), 256, 0, stream>>>(
      yS, MN, WoutS, WOU, out, DINNER, DMODEL / 128);
}

// Round 5
// 507.472 us; speedup vs baseline: 2.1236x; 1.2783x over previous
//
#include <hip/hip_runtime.h>
#include <hip/hip_bf16.h>
#include <math.h>

#define BB 8
#define LL 2048
#define DMODEL 512
#define DINNER 1024
#define DSSM 512
#define NST 16
#define DTR 32
#define CCH 64            // scan chunks
#define LC (LL / CCH)     // 32 steps per chunk
#define BDN (BB * DSSM * NST)  // 65536 scan lanes

typedef short short8 __attribute__((ext_vector_type(8)));
typedef float f32x4 __attribute__((ext_vector_type(4)));

// ---- bf16 helpers (RNE, bit-level) ----------------------------------------
__device__ __forceinline__ unsigned short f2bf(float f) {
  unsigned u = __float_as_uint(f);
  u += 0x7FFFu + ((u >> 16) & 1u);
  return (unsigned short)(u >> 16);
}
__device__ __forceinline__ float bf2f(unsigned short s) {
  return __uint_as_float(((unsigned)s) << 16);
}

__device__ __forceinline__ void gload16(const void* g, void* l) {
  __builtin_amdgcn_global_load_lds(
      (const __attribute__((address_space(1))) void*)g,
      (__attribute__((address_space(3))) void*)l, 16, 0, 0);
}

// ---------------------------------------------------------------------------
// split-bf16 MFMA GEMM: C[M,N](fp32) = (Ahi+Alo)[M,K] * (Whi+Wlo)[N,K]^T
// 128x128 tile, BK=32, 256 thr (4 waves, 2x2 of 64x64). LDS rows = 128B:
// [hi k0..31 | lo k0..31], granule-XOR-swizzled (source-side + read-side).
// 3 MFMAs per (m,n): hi*hi + hi*lo + lo*hi.
// ---------------------------------------------------------------------------
__global__ __launch_bounds__(256) void gemm_mfma_split(
    const unsigned short* __restrict__ Ab, size_t planeA,
    const unsigned short* __restrict__ Wb, size_t planeW,
    float* __restrict__ Cout, int K, int NBN) {
  __shared__ unsigned short tA[128 * 64];
  __shared__ unsigned short tW[128 * 64];
  const int tid = threadIdx.x;
  const int ln = tid & 63;
  const int wv = tid >> 6;
  const int wr = wv >> 1, wc = wv & 1;
  const int lr = ln & 15, kc = ln >> 4;

  const int nwg = gridDim.x;
  const int q = nwg >> 3;
  const int bid = blockIdx.x;
  const int wg = (bid & 7) * q + (bid >> 3);
  const int mblk = wg / NBN, nblk = wg % NBN;
  const size_t m0 = (size_t)mblk * 128, n0 = (size_t)nblk * 128;

  f32x4 acc[4][4];
#pragma unroll
  for (int m = 0; m < 4; ++m)
#pragma unroll
    for (int n = 0; n < 4; ++n)
#pragma unroll
      for (int j = 0; j < 4; ++j) acc[m][n][j] = 0.f;

  const int wbase = (tid & 0xC0) << 4;  // wave-uniform byte base

  for (int k0 = 0; k0 < K; k0 += 32) {
#pragma unroll
    for (int it = 0; it < 4; ++it) {
      const int gi = it * 256 + tid;
      const int r = gi >> 3, s = gi & 7, g = s ^ (r & 7);
      const size_t off = (size_t)(g >> 2) * planeA + (m0 + r) * (size_t)K
                       + (size_t)(k0 + (g & 3) * 8);
      gload16(Ab + off, (char*)tA + it * 4096 + wbase);
    }
#pragma unroll
    for (int it = 0; it < 4; ++it) {
      const int gi = it * 256 + tid;
      const int r = gi >> 3, s = gi & 7, g = s ^ (r & 7);
      const size_t off = (size_t)(g >> 2) * planeW + (n0 + r) * (size_t)K
                       + (size_t)(k0 + (g & 3) * 8);
      gload16(Wb + off, (char*)tW + it * 4096 + wbase);
    }
    __syncthreads();

    short8 ah[4], al[4], wh[4], wl[4];
#pragma unroll
    for (int m = 0; m < 4; ++m) {
      const int ra = wr * 64 + m * 16 + lr;
      const int hs = kc ^ (ra & 7);
      const char* base = (const char*)tA + ra * 128;
      ah[m] = *(const short8*)(base + hs * 16);
      al[m] = *(const short8*)(base + (hs ^ 4) * 16);
    }
#pragma unroll
    for (int n = 0; n < 4; ++n) {
      const int rb = wc * 64 + n * 16 + lr;
      const int hs = kc ^ (rb & 7);
      const char* base = (const char*)tW + rb * 128;
      wh[n] = *(const short8*)(base + hs * 16);
      wl[n] = *(const short8*)(base + (hs ^ 4) * 16);
    }
#pragma unroll
    for (int m = 0; m < 4; ++m)
#pragma unroll
      for (int n = 0; n < 4; ++n) {
        acc[m][n] = __builtin_amdgcn_mfma_f32_16x16x32_bf16(ah[m], wh[n], acc[m][n], 0, 0, 0);
        acc[m][n] = __builtin_amdgcn_mfma_f32_16x16x32_bf16(ah[m], wl[n], acc[m][n], 0, 0, 0);
        acc[m][n] = __builtin_amdgcn_mfma_f32_16x16x32_bf16(al[m], wh[n], acc[m][n], 0, 0, 0);
      }
    __syncthreads();
  }

  const int ldc = NBN * 128;
#pragma unroll
  for (int m = 0; m < 4; ++m) {
    const size_t row0 = m0 + wr * 64 + m * 16 + kc * 4;
#pragma unroll
    for (int n = 0; n < 4; ++n) {
      const size_t col = n0 + wc * 64 + n * 16 + lr;
#pragma unroll
      for (int j = 0; j < 4; ++j)
        Cout[(row0 + j) * (size_t)ldc + col] = acc[m][n][j];
    }
  }
}

// ---------------------------------------------------------------------------
// fp32 -> (hi, lo) bf16 planes.
// ---------------------------------------------------------------------------
__global__ __launch_bounds__(256) void split_kernel(const float* __restrict__ in,
    unsigned short* __restrict__ hi, unsigned short* __restrict__ lo, int n4) {
  int i = blockIdx.x * 256 + threadIdx.x;
  const int str = gridDim.x * 256;
  for (; i < n4; i += str) {
    const float4 v = ((const float4*)in)[i];
    ushort4 h, l;
    h.x = f2bf(v.x); l.x = f2bf(v.x - bf2f(h.x));
    h.y = f2bf(v.y); l.y = f2bf(v.y - bf2f(h.y));
    h.z = f2bf(v.z); l.z = f2bf(v.z - bf2f(h.z));
    h.w = f2bf(v.w); l.w = f2bf(v.w - bf2f(h.w));
    ((ushort4*)hi)[i] = h;
    ((ushort4*)lo)[i] = l;
  }
}

// ---------------------------------------------------------------------------
// Generic fp32 GEMM (kept for the small x_dbl projection, N=64).
// ---------------------------------------------------------------------------
template<int GM, int GN>
__global__ __launch_bounds__(256) void gemm_tn(const float* __restrict__ A,
    const float* __restrict__ W, float* __restrict__ C,
    int K, int lda, int ldw, int ldc) {
  constexpr int BM = 64 * GM, BN = 64 * GN;
  __shared__ float As[16][BM + 4];
  __shared__ float Ws[16][BN + 4];
  const int tid = threadIdx.x;
  const int tx = tid & 15, ty = tid >> 4;
  const long m0 = (long)blockIdx.y * BM, n0 = (long)blockIdx.x * BN;

  float acc[GM * 4][GN * 4];
#pragma unroll
  for (int i = 0; i < GM * 4; i++)
#pragma unroll
    for (int j = 0; j < GN * 4; j++) acc[i][j] = 0.f;

  for (int k0 = 0; k0 < K; k0 += 16) {
#pragma unroll
    for (int it = 0; it < GM; it++) {
      int idx = tid + it * 256;
      int row = idx >> 2, c4 = (idx & 3) << 2;
      float4 v = *(const float4*)(A + (m0 + row) * (long)lda + k0 + c4);
      As[c4 + 0][row] = v.x; As[c4 + 1][row] = v.y;
      As[c4 + 2][row] = v.z; As[c4 + 3][row] = v.w;
    }
#pragma unroll
    for (int it = 0; it < GN; it++) {
      int idx = tid + it * 256;
      int row = idx >> 2, c4 = (idx & 3) << 2;
      float4 v = *(const float4*)(W + (n0 + row) * (long)ldw + k0 + c4);
      Ws[c4 + 0][row] = v.x; Ws[c4 + 1][row] = v.y;
      Ws[c4 + 2][row] = v.z; Ws[c4 + 3][row] = v.w;
    }
    __syncthreads();
#pragma unroll
    for (int k = 0; k < 16; k++) {
      float a[GM * 4], bv[GN * 4];
#pragma unroll
      for (int g = 0; g < GM; g++) {
        float4 t4 = *(const float4*)&As[k][g * 64 + ty * 4];
        a[g * 4 + 0] = t4.x; a[g * 4 + 1] = t4.y;
        a[g * 4 + 2] = t4.z; a[g * 4 + 3] = t4.w;
      }
#pragma unroll
      for (int g = 0; g < GN; g++) {
        float4 t4 = *(const float4*)&Ws[k][g * 64 + tx * 4];
        bv[g * 4 + 0] = t4.x; bv[g * 4 + 1] = t4.y;
        bv[g * 4 + 2] = t4.z; bv[g * 4 + 3] = t4.w;
      }
#pragma unroll
      for (int i = 0; i < GM * 4; i++)
#pragma unroll
        for (int j = 0; j < GN * 4; j++)
          acc[i][j] += a[i] * bv[j];
    }
    __syncthreads();
  }

#pragma unroll
  for (int gm = 0; gm < GM; gm++)
#pragma unroll
    for (int i = 0; i < 4; i++) {
      long row = m0 + gm * 64 + ty * 4 + i;
#pragma unroll
      for (int gn = 0; gn < GN; gn++) {
        float4 o;
        o.x = acc[gm * 4 + i][gn * 4 + 0];
        o.y = acc[gm * 4 + i][gn * 4 + 1];
        o.z = acc[gm * 4 + i][gn * 4 + 2];
        o.w = acc[gm * 4 + i][gn * 4 + 3];
        *(float4*)(C + row * (long)ldc + n0 + gn * 64 + tx * 4) = o;
      }
    }
}

// ---------------------------------------------------------------------------
// Depthwise conv + bias + SiLU. x-half -> xc (fp32); z-half -> y hi/lo planes.
// ---------------------------------------------------------------------------
__global__ __launch_bounds__(256) void conv_silu_kernel(
    const float* __restrict__ xz,
    const float* __restrict__ cxw, const float* __restrict__ cxb,
    const float* __restrict__ czw, const float* __restrict__ czb,
    float* __restrict__ xc,
    unsigned short* __restrict__ yHi, unsigned short* __restrict__ yLo) {
  const int c = blockIdx.x * 256 + threadIdx.x;  // 0..1023
  const int l = blockIdx.y;
  const int b = blockIdx.z;
  const float* base = xz + ((size_t)b * LL) * DINNER + c;
  float w0, w1, w2, w3, bias;
  if (c < DSSM) {
    w0 = cxw[c * 4 + 0]; w1 = cxw[c * 4 + 1]; w2 = cxw[c * 4 + 2]; w3 = cxw[c * 4 + 3];
    bias = cxb[c];
  } else {
    int cz = c - DSSM;
    w0 = czw[cz * 4 + 0]; w1 = czw[cz * 4 + 1]; w2 = czw[cz * 4 + 2]; w3 = czw[cz * 4 + 3];
    bias = czb[cz];
  }
  float acc = bias;
  int li;
  li = l - 1; if (li >= 0)  acc += base[(size_t)li * DINNER] * w0;
  li = l;                   acc += base[(size_t)li * DINNER] * w1;
  li = l + 1; if (li < LL)  acc += base[(size_t)li * DINNER] * w2;
  li = l + 2; if (li < LL)  acc += base[(size_t)li * DINNER] * w3;
  float y = acc / (1.f + expf(-acc));  // SiLU
  if (c < DSSM) {
    xc[((size_t)b * LL + l) * DSSM + c] = y;
  } else {
    const size_t idx = ((size_t)b * LL + l) * DINNER + c;
    unsigned short h = f2bf(y);
    yHi[idx] = h;
    yLo[idx] = f2bf(y - bf2f(h));
  }
}

// ---------------------------------------------------------------------------
// dt = W_dt @ x_dbl[:,:32] ; delta = softplus(dt + b_dt) ;
// k2 = sum(k^2) ; eps = delta / (1 + delta*k2).  One block per (b,l).
// ---------------------------------------------------------------------------
__global__ __launch_bounds__(256) void dteps_kernel(
    const float* __restrict__ xdbl, const float* __restrict__ W_dt,
    const float* __restrict__ b_dt, float* __restrict__ eps) {
  const long bl = blockIdx.x;
  __shared__ float sd[64];
  __shared__ float sk2;
  const int t = threadIdx.x;
  if (t < 64) sd[t] = xdbl[bl * 64 + t];
  __syncthreads();
  if (t == 0) {
    float s = 0.f;
#pragma unroll
    for (int n = 0; n < NST; n++) { float kv = sd[32 + n]; s += kv * kv; }
    sk2 = s;
  }
  __syncthreads();
  const float k2 = sk2;
#pragma unroll
  for (int rep = 0; rep < 2; rep++) {
    const int d = t + rep * 256;
    float dt = b_dt[d];
    const float4* wr = (const float4*)&W_dt[d * DTR];
#pragma unroll
    for (int r4 = 0; r4 < 8; r4++) {
      float4 w = wr[r4];
      dt += w.x * sd[r4 * 4 + 0] + w.y * sd[r4 * 4 + 1] +
            w.z * sd[r4 * 4 + 2] + w.w * sd[r4 * 4 + 3];
    }
    float delta = (dt > 20.f) ? dt : log1pf(expf(dt));
    eps[bl * DSSM + d] = delta / (1.f + delta * k2);
  }
}

// ---------------------------------------------------------------------------
// Chunked scan, thread-per-(b,d): 16 n-states in registers.
//   a_n = 1 - eps*k_n^2 ; S_n = a_n*S_n + eps*u*k_n ; y = sum_n S_n*q_n.
// k/q loads are wave-uniform (block shares (b,l)) -> scalar pipe.
// passA: per-chunk A_n = prod a, B_n = local end state. Grid (2, 8, CCH).
// passB: serial exclusive combine over chunks -> S0 per chunk. 65536 thr.
// passC: start from S0, recompute chunk, emit y (split bf16 planes).
// ---------------------------------------------------------------------------
__global__ __launch_bounds__(256) void scan_passA(
    const float* __restrict__ eps, const float* __restrict__ xc,
    const float* __restrict__ xdbl,
    float* __restrict__ Ach, float* __restrict__ Bch) {
  const int d = blockIdx.x * 256 + threadIdx.x;
  const int b = blockIdx.y, ch = blockIdx.z;
  const size_t bl0 = (size_t)b * LL + (size_t)ch * LC;
  const float* ep = eps + bl0 * DSSM + d;
  const float* up = xc + bl0 * DSSM + d;
  const float* kq = xdbl + bl0 * 64;
  float A[16], S[16];
#pragma unroll
  for (int n = 0; n < 16; n++) { A[n] = 1.f; S[n] = 0.f; }
#pragma unroll 2
  for (int j = 0; j < LC; j++) {
    const float e = ep[(size_t)j * DSSM];
    const float u = up[(size_t)j * DSSM];
    const float* kj = kq + j * 64 + 32;   // uniform address
#pragma unroll
    for (int n = 0; n < 16; n++) {
      const float k = kj[n];
      const float t0 = e * k;
      const float a = fmaf(-t0, k, 1.f);
      A[n] *= a;
      S[n] = fmaf(S[n], a, t0 * u);
    }
  }
  const size_t base = (size_t)ch * BDN + (((size_t)b * DSSM + d) << 4);
#pragma unroll
  for (int n4 = 0; n4 < 4; n4++) {
    ((float4*)(Ach + base))[n4] =
        make_float4(A[4 * n4], A[4 * n4 + 1], A[4 * n4 + 2], A[4 * n4 + 3]);
    ((float4*)(Bch + base))[n4] =
        make_float4(S[4 * n4], S[4 * n4 + 1], S[4 * n4 + 2], S[4 * n4 + 3]);
  }
}

__global__ __launch_bounds__(256) void scan_passB(
    const float* __restrict__ Ach, const float* __restrict__ Bch,
    float* __restrict__ S0) {
  const size_t i = (size_t)blockIdx.x * 256 + threadIdx.x;  // 65536 lanes
  float S = 0.f;
  for (int ch = 0; ch < CCH; ch++) {
    const size_t off = (size_t)ch * BDN + i;
    const float a = Ach[off];
    const float bv = Bch[off];
    S0[off] = S;           // exclusive: carry INTO chunk ch
    S = fmaf(S, a, bv);
  }
}

__global__ __launch_bounds__(256) void scan_passC(
    const float* __restrict__ eps, const float* __restrict__ xc,
    const float* __restrict__ xdbl, const float* __restrict__ D_skip,
    const float* __restrict__ S0,
    unsigned short* __restrict__ yHi, unsigned short* __restrict__ yLo) {
  const int d = blockIdx.x * 256 + threadIdx.x;
  const int b = blockIdx.y, ch = blockIdx.z;
  const size_t bl0 = (size_t)b * LL + (size_t)ch * LC;
  const float* ep = eps + bl0 * DSSM + d;
  const float* up = xc + bl0 * DSSM + d;
  const float* kq = xdbl + bl0 * 64;
  unsigned short* ypH = yHi + bl0 * DINNER + d;
  unsigned short* ypL = yLo + bl0 * DINNER + d;
  const float Dv = D_skip[d];
  const size_t base = (size_t)ch * BDN + (((size_t)b * DSSM + d) << 4);
  float S[16];
#pragma unroll
  for (int n4 = 0; n4 < 4; n4++) {
    const float4 v = ((const float4*)(S0 + base))[n4];
    S[4 * n4 + 0] = v.x; S[4 * n4 + 1] = v.y;
    S[4 * n4 + 2] = v.z; S[4 * n4 + 3] = v.w;
  }
#pragma unroll 2
  for (int j = 0; j < LC; j++) {
    const float e = ep[(size_t)j * DSSM];
    const float u = up[(size_t)j * DSSM];
    const float* kj = kq + j * 64 + 32;   // uniform; q at kj[16+n]
#pragma unroll
    for (int n = 0; n < 16; n++) {
      const float k = kj[n];
      const float t0 = e * k;
      const float a = fmaf(-t0, k, 1.f);
      S[n] = fmaf(S[n], a, t0 * u);
    }
    float y0 = 0.f, y1 = 0.f, y2 = 0.f, y3 = 0.f;
#pragma unroll
    for (int n = 0; n < 16; n += 4) {
      y0 = fmaf(S[n + 0], kj[16 + n + 0], y0);
      y1 = fmaf(S[n + 1], kj[16 + n + 1], y1);
      y2 = fmaf(S[n + 2], kj[16 + n + 2], y2);
      y3 = fmaf(S[n + 3], kj[16 + n + 3], y3);
    }
    const float yv = fmaf(Dv, u, (y0 + y1) + (y2 + y3));
    const unsigned short h = f2bf(yv);
    ypH[(size_t)j * DINNER] = h;
    ypL[(size_t)j * DINNER] = f2bf(yv - bf2f(h));
  }
}

// ---------------------------------------------------------------------------
extern "C" void kernel_launch(void* const* d_in, const int* in_sizes, int n_in,
                              void* d_out, int out_size, void* d_ws, size_t ws_size,
                              hipStream_t stream) {
  const float* hidden  = (const float*)d_in[0];
  const float* W_in    = (const float*)d_in[1];
  const float* cxw     = (const float*)d_in[2];
  const float* cxb     = (const float*)d_in[3];
  const float* czw     = (const float*)d_in[4];
  const float* czb     = (const float*)d_in[5];
  const float* W_xproj = (const float*)d_in[6];
  const float* W_dt    = (const float*)d_in[7];
  const float* b_dt    = (const float*)d_in[8];
  const float* D_skip  = (const float*)d_in[9];
  const float* W_out   = (const float*)d_in[10];
  float* out = (float*)d_out;

  const size_t ML  = (size_t)BB * LL;      // 16384
  const size_t MK5 = ML * DSSM;            // 8.4M
  const size_t MN  = ML * DINNER;          // 16.8M
  const size_t WIN = (size_t)DINNER * DMODEL;
  const size_t WOU = (size_t)DMODEL * DINNER;

  unsigned short* hidS  = (unsigned short*)d_ws;   // 2*MK5 shorts
  unsigned short* WinS  = hidS + 2 * MK5;
  unsigned short* WoutS = WinS + 2 * WIN;
  float* xz   = (float*)(WoutS + 2 * WOU);         // MN floats
  float* xc   = xz + MN;                           // MK5 floats
  float* xdbl = xc + MK5;                          // ML*64 floats
  unsigned short* yS = (unsigned short*)(xdbl + ML * 64);  // 2*MN shorts
  float* eps = xz;                                 // alias: xz[0:MK5] dead after conv
  float* S0  = xz + MK5;                           // alias: xz z-half dead after conv
  float* Ach = (float*)hidS;                       // alias: hidS dead after GEMM1
  float* Bch = Ach + (size_t)CCH * BDN;            // exact fit in hidS region

  // 0) fp32 -> split-bf16 planes
  split_kernel<<<2048, 256, 0, stream>>>(hidden, hidS, hidS + MK5, (int)(MK5 / 4));
  split_kernel<<<512, 256, 0, stream>>>(W_in, WinS, WinS + WIN, (int)(WIN / 4));
  split_kernel<<<512, 256, 0, stream>>>(W_out, WoutS, WoutS + WOU, (int)(WOU / 4));

  // 1) xz = hidden @ W_in^T   (MFMA split-bf16; M=16384, N=1024, K=512)
  gemm_mfma_split<<<(16384 / 128) * (1024 / 128), 256, 0, stream>>>(
      hidS, MK5, WinS, WIN, xz, DMODEL, DINNER / 128);

  // 2) depthwise conv + SiLU
  conv_silu_kernel<<<dim3(DINNER / 256, LL, BB), 256, 0, stream>>>(
      xz, cxw, cxb, czw, czb, xc, yS, yS + MN);

  // 3) x_dbl = xc @ W_xproj^T  (fp32, N=64)
  gemm_tn<2, 1><<<dim3(1, ML / 128), 256, 0, stream>>>(
      xc, W_xproj, xdbl, DSSM, DSSM, DSSM, 64);

  // 4) dt -> softplus -> eps
  dteps_kernel<<<dim3((unsigned)ML), 256, 0, stream>>>(xdbl, W_dt, b_dt, eps);

  // 5) chunked scan
  scan_passA<<<dim3(2, BB, CCH), 256, 0, stream>>>(eps, xc, xdbl, Ach, Bch);
  scan_passB<<<dim3(BDN / 256), 256, 0, stream>>>(Ach, Bch, S0);
  scan_passC<<<dim3(2, BB, CCH), 256, 0, stream>>>(
      eps, xc, xdbl, D_skip, S0, yS, yS + MN);

  // 6) out = ycat @ W_out^T  (MFMA split-bf16; M=16384, N=512, K=1024)
  gemm_mfma_split<<<(16384 / 128) * (512 / 128), 256, 0, stream>>>(
      yS, MN, WoutS, WOU, out, DINNER, DMODEL / 128);
}

// Round 6
// 428.190 us; speedup vs baseline: 2.5168x; 1.1852x over previous
//
#include <hip/hip_runtime.h>
#include <hip/hip_bf16.h>
#include <math.h>

#define BB 8
#define LL 2048
#define DMODEL 512
#define DINNER 1024
#define DSSM 512
#define NST 16
#define DTR 32
#define CCH 64            // scan chunks
#define LC (LL / CCH)     // 32 steps per chunk
#define BDN (BB * DSSM * NST)  // 65536 scan lanes

typedef short short8 __attribute__((ext_vector_type(8)));
typedef float f32x4 __attribute__((ext_vector_type(4)));

// ---- bf16 helpers (RNE, bit-level) ----------------------------------------
__device__ __forceinline__ unsigned short f2bf(float f) {
  unsigned u = __float_as_uint(f);
  u += 0x7FFFu + ((u >> 16) & 1u);
  return (unsigned short)(u >> 16);
}
__device__ __forceinline__ float bf2f(unsigned short s) {
  return __uint_as_float(((unsigned)s) << 16);
}

__device__ __forceinline__ void gload16(const void* g, void* l) {
  __builtin_amdgcn_global_load_lds(
      (const __attribute__((address_space(1))) void*)g,
      (__attribute__((address_space(3))) void*)l, 16, 0, 0);
}

// ---------------------------------------------------------------------------
// split-bf16 MFMA GEMM: C[M,N](fp32) = (Ahi+Alo)[M,K] * (Whi+Wlo)[N,K]^T
// 128x128 tile, BK=32, 256 thr (4 waves, 2x2 of 64x64). LDS rows = 128B:
// [hi k0..31 | lo k0..31], granule-XOR-swizzled (source-side + read-side).
// 3 MFMAs per (m,n): hi*hi + hi*lo + lo*hi.
// ---------------------------------------------------------------------------
__global__ __launch_bounds__(256) void gemm_mfma_split(
    const unsigned short* __restrict__ Ab, size_t planeA,
    const unsigned short* __restrict__ Wb, size_t planeW,
    float* __restrict__ Cout, int K, int NBN) {
  __shared__ unsigned short tA[128 * 64];
  __shared__ unsigned short tW[128 * 64];
  const int tid = threadIdx.x;
  const int ln = tid & 63;
  const int wv = tid >> 6;
  const int wr = wv >> 1, wc = wv & 1;
  const int lr = ln & 15, kc = ln >> 4;

  const int nwg = gridDim.x;
  const int q = nwg >> 3;
  const int bid = blockIdx.x;
  const int wg = (bid & 7) * q + (bid >> 3);
  const int mblk = wg / NBN, nblk = wg % NBN;
  const size_t m0 = (size_t)mblk * 128, n0 = (size_t)nblk * 128;

  f32x4 acc[4][4];
#pragma unroll
  for (int m = 0; m < 4; ++m)
#pragma unroll
    for (int n = 0; n < 4; ++n)
#pragma unroll
      for (int j = 0; j < 4; ++j) acc[m][n][j] = 0.f;

  const int wbase = (tid & 0xC0) << 4;  // wave-uniform byte base

  for (int k0 = 0; k0 < K; k0 += 32) {
#pragma unroll
    for (int it = 0; it < 4; ++it) {
      const int gi = it * 256 + tid;
      const int r = gi >> 3, s = gi & 7, g = s ^ (r & 7);
      const size_t off = (size_t)(g >> 2) * planeA + (m0 + r) * (size_t)K
                       + (size_t)(k0 + (g & 3) * 8);
      gload16(Ab + off, (char*)tA + it * 4096 + wbase);
    }
#pragma unroll
    for (int it = 0; it < 4; ++it) {
      const int gi = it * 256 + tid;
      const int r = gi >> 3, s = gi & 7, g = s ^ (r & 7);
      const size_t off = (size_t)(g >> 2) * planeW + (n0 + r) * (size_t)K
                       + (size_t)(k0 + (g & 3) * 8);
      gload16(Wb + off, (char*)tW + it * 4096 + wbase);
    }
    __syncthreads();

    short8 ah[4], al[4], wh[4], wl[4];
#pragma unroll
    for (int m = 0; m < 4; ++m) {
      const int ra = wr * 64 + m * 16 + lr;
      const int hs = kc ^ (ra & 7);
      const char* base = (const char*)tA + ra * 128;
      ah[m] = *(const short8*)(base + hs * 16);
      al[m] = *(const short8*)(base + (hs ^ 4) * 16);
    }
#pragma unroll
    for (int n = 0; n < 4; ++n) {
      const int rb = wc * 64 + n * 16 + lr;
      const int hs = kc ^ (rb & 7);
      const char* base = (const char*)tW + rb * 128;
      wh[n] = *(const short8*)(base + hs * 16);
      wl[n] = *(const short8*)(base + (hs ^ 4) * 16);
    }
#pragma unroll
    for (int m = 0; m < 4; ++m)
#pragma unroll
      for (int n = 0; n < 4; ++n) {
        acc[m][n] = __builtin_amdgcn_mfma_f32_16x16x32_bf16(ah[m], wh[n], acc[m][n], 0, 0, 0);
        acc[m][n] = __builtin_amdgcn_mfma_f32_16x16x32_bf16(ah[m], wl[n], acc[m][n], 0, 0, 0);
        acc[m][n] = __builtin_amdgcn_mfma_f32_16x16x32_bf16(al[m], wh[n], acc[m][n], 0, 0, 0);
      }
    __syncthreads();
  }

  const int ldc = NBN * 128;
#pragma unroll
  for (int m = 0; m < 4; ++m) {
    const size_t row0 = m0 + wr * 64 + m * 16 + kc * 4;
#pragma unroll
    for (int n = 0; n < 4; ++n) {
      const size_t col = n0 + wc * 64 + n * 16 + lr;
#pragma unroll
      for (int j = 0; j < 4; ++j)
        Cout[(row0 + j) * (size_t)ldc + col] = acc[m][n][j];
    }
  }
}

// ---------------------------------------------------------------------------
// fp32 -> (hi, lo) bf16 planes.
// ---------------------------------------------------------------------------
__global__ __launch_bounds__(256) void split_kernel(const float* __restrict__ in,
    unsigned short* __restrict__ hi, unsigned short* __restrict__ lo, int n4) {
  int i = blockIdx.x * 256 + threadIdx.x;
  const int str = gridDim.x * 256;
  for (; i < n4; i += str) {
    const float4 v = ((const float4*)in)[i];
    ushort4 h, l;
    h.x = f2bf(v.x); l.x = f2bf(v.x - bf2f(h.x));
    h.y = f2bf(v.y); l.y = f2bf(v.y - bf2f(h.y));
    h.z = f2bf(v.z); l.z = f2bf(v.z - bf2f(h.z));
    h.w = f2bf(v.w); l.w = f2bf(v.w - bf2f(h.w));
    ((ushort4*)hi)[i] = h;
    ((ushort4*)lo)[i] = l;
  }
}

// ---------------------------------------------------------------------------
// x_dbl projection GEMM: C[16384,64] = A[16384,512] * W[64,512]^T  (fp32).
// BM=16 -> 1024 blocks. As staged [k][m] (conflict-free float4 reads),
// Ws staged [k][n] (2-way read, free). 4 outputs/thread.
// ---------------------------------------------------------------------------
__global__ __launch_bounds__(256) void gemm_xproj(
    const float* __restrict__ A, const float* __restrict__ W,
    float* __restrict__ C) {
  __shared__ float As[32][16];   // [k][m]
  __shared__ float Ws[32][64];   // [k][n]
  const int t = threadIdx.x;
  const int tn = t & 63, tm = t >> 6;
  const size_t m0 = (size_t)blockIdx.x * 16;
  float acc[4] = {0.f, 0.f, 0.f, 0.f};

  for (int k0 = 0; k0 < 512; k0 += 32) {
    if (t < 128) {
      const int r = t >> 3, c4 = (t & 7) << 2;
      const float4 v = *(const float4*)(A + (m0 + r) * 512 + k0 + c4);
      As[c4 + 0][r] = v.x; As[c4 + 1][r] = v.y;
      As[c4 + 2][r] = v.z; As[c4 + 3][r] = v.w;
    }
#pragma unroll
    for (int rep = 0; rep < 2; rep++) {
      const int f = t + rep * 256;           // 0..511
      const int n = f >> 3, c4 = (f & 7) << 2;
      const float4 v = *(const float4*)(W + n * 512 + k0 + c4);
      Ws[c4 + 0][n] = v.x; Ws[c4 + 1][n] = v.y;
      Ws[c4 + 2][n] = v.z; Ws[c4 + 3][n] = v.w;
    }
    __syncthreads();
#pragma unroll
    for (int k = 0; k < 32; k++) {
      const float4 a4 = *(const float4*)&As[k][tm * 4];
      const float w = Ws[k][tn];
      acc[0] = fmaf(a4.x, w, acc[0]);
      acc[1] = fmaf(a4.y, w, acc[1]);
      acc[2] = fmaf(a4.z, w, acc[2]);
      acc[3] = fmaf(a4.w, w, acc[3]);
    }
    __syncthreads();
  }
#pragma unroll
  for (int i = 0; i < 4; i++)
    C[(m0 + tm * 4 + i) * 64 + tn] = acc[i];
}

// ---------------------------------------------------------------------------
// Depthwise conv + bias + SiLU. x-half -> xc (fp32); z-half -> y hi/lo planes.
// ---------------------------------------------------------------------------
__global__ __launch_bounds__(256) void conv_silu_kernel(
    const float* __restrict__ xz,
    const float* __restrict__ cxw, const float* __restrict__ cxb,
    const float* __restrict__ czw, const float* __restrict__ czb,
    float* __restrict__ xc,
    unsigned short* __restrict__ yHi, unsigned short* __restrict__ yLo) {
  const int c = blockIdx.x * 256 + threadIdx.x;  // 0..1023
  const int l = blockIdx.y;
  const int b = blockIdx.z;
  const float* base = xz + ((size_t)b * LL) * DINNER + c;
  float w0, w1, w2, w3, bias;
  if (c < DSSM) {
    w0 = cxw[c * 4 + 0]; w1 = cxw[c * 4 + 1]; w2 = cxw[c * 4 + 2]; w3 = cxw[c * 4 + 3];
    bias = cxb[c];
  } else {
    int cz = c - DSSM;
    w0 = czw[cz * 4 + 0]; w1 = czw[cz * 4 + 1]; w2 = czw[cz * 4 + 2]; w3 = czw[cz * 4 + 3];
    bias = czb[cz];
  }
  float acc = bias;
  int li;
  li = l - 1; if (li >= 0)  acc += base[(size_t)li * DINNER] * w0;
  li = l;                   acc += base[(size_t)li * DINNER] * w1;
  li = l + 1; if (li < LL)  acc += base[(size_t)li * DINNER] * w2;
  li = l + 2; if (li < LL)  acc += base[(size_t)li * DINNER] * w3;
  float y = acc / (1.f + expf(-acc));  // SiLU
  if (c < DSSM) {
    xc[((size_t)b * LL + l) * DSSM + c] = y;
  } else {
    const size_t idx = ((size_t)b * LL + l) * DINNER + c;
    unsigned short h = f2bf(y);
    yHi[idx] = h;
    yLo[idx] = f2bf(y - bf2f(h));
  }
}

// ---------------------------------------------------------------------------
// dteps v2: 16 (b,l) rows per block, grid 1024.
//  - W_dt staged coalesced into padded LDS once, then register-persisted
//    (2 d-rows/thread) -> kills the per-(b,l) uncoalesced W_dt gather.
//  - k2 via 16-lane shfl reduce; dt dot from broadcast LDS reads.
// ---------------------------------------------------------------------------
__global__ __launch_bounds__(256) void dteps_kernel(
    const float* __restrict__ xdbl, const float* __restrict__ W_dt,
    const float* __restrict__ b_dt, float* __restrict__ eps) {
  __shared__ float sW[512 * 36];  // padded rows: stride 36 floats
  __shared__ float sd[16 * 64];
  __shared__ float sk2[16];
  const int t = threadIdx.x;
  const size_t bl0 = (size_t)blockIdx.x * 16;

  // stage W_dt (512x32) coalesced -> padded LDS
#pragma unroll
  for (int it = 0; it < 16; it++) {
    const int i = it * 256 + t;          // float4 index 0..4095
    const int d = i >> 3, j = i & 7;
    const float4 v = ((const float4*)W_dt)[i];
    *(float4*)&sW[d * 36 + j * 4] = v;
  }
  // stage x_dbl tile (16 rows x 64)
  {
    const float4 v = ((const float4*)(xdbl + bl0 * 64))[t];
    *(float4*)&sd[t * 4] = v;
  }
  __syncthreads();

  // k2 per row: thread (il = t>>4, n = t&15)
  {
    const int il = t >> 4, n = t & 15;
    float v = sd[il * 64 + 32 + n];
    v *= v;
    v += __shfl_xor(v, 1); v += __shfl_xor(v, 2);
    v += __shfl_xor(v, 4); v += __shfl_xor(v, 8);
    if (n == 0) sk2[il] = v;
  }

  // register-persist this thread's two W_dt rows
  const int d0 = t, d1 = t + 256;
  float W0[32], W1[32];
#pragma unroll
  for (int j4 = 0; j4 < 8; j4++) {
    *(float4*)&W0[j4 * 4] = *(const float4*)&sW[d0 * 36 + j4 * 4];
    *(float4*)&W1[j4 * 4] = *(const float4*)&sW[d1 * 36 + j4 * 4];
  }
  const float b0 = b_dt[d0], b1 = b_dt[d1];
  __syncthreads();

#pragma unroll
  for (int il = 0; il < 16; il++) {
    float dl[32];
#pragma unroll
    for (int j4 = 0; j4 < 8; j4++)
      *(float4*)&dl[j4 * 4] = *(const float4*)&sd[il * 64 + j4 * 4];
    const float k2 = sk2[il];
    float dt0 = b0, dt1 = b1;
#pragma unroll
    for (int r = 0; r < 32; r++) {
      dt0 = fmaf(W0[r], dl[r], dt0);
      dt1 = fmaf(W1[r], dl[r], dt1);
    }
    const float del0 = (dt0 > 20.f) ? dt0 : log1pf(expf(dt0));
    const float del1 = (dt1 > 20.f) ? dt1 : log1pf(expf(dt1));
    const size_t row = (bl0 + il) * DSSM;
    eps[row + d0] = del0 / (1.f + del0 * k2);
    eps[row + d1] = del1 / (1.f + del1 * k2);
  }
}

// ---------------------------------------------------------------------------
// Chunked scan, thread-per-(b,d): 16 n-states in registers.
// ---------------------------------------------------------------------------
__global__ __launch_bounds__(256) void scan_passA(
    const float* __restrict__ eps, const float* __restrict__ xc,
    const float* __restrict__ xdbl,
    float* __restrict__ Ach, float* __restrict__ Bch) {
  const int d = blockIdx.x * 256 + threadIdx.x;
  const int b = blockIdx.y, ch = blockIdx.z;
  const size_t bl0 = (size_t)b * LL + (size_t)ch * LC;
  const float* ep = eps + bl0 * DSSM + d;
  const float* up = xc + bl0 * DSSM + d;
  const float* kq = xdbl + bl0 * 64;
  float A[16], S[16];
#pragma unroll
  for (int n = 0; n < 16; n++) { A[n] = 1.f; S[n] = 0.f; }
#pragma unroll 2
  for (int j = 0; j < LC; j++) {
    const float e = ep[(size_t)j * DSSM];
    const float u = up[(size_t)j * DSSM];
    const float* kj = kq + j * 64 + 32;   // uniform address
#pragma unroll
    for (int n = 0; n < 16; n++) {
      const float k = kj[n];
      const float t0 = e * k;
      const float a = fmaf(-t0, k, 1.f);
      A[n] *= a;
      S[n] = fmaf(S[n], a, t0 * u);
    }
  }
  const size_t base = (size_t)ch * BDN + (((size_t)b * DSSM + d) << 4);
#pragma unroll
  for (int n4 = 0; n4 < 4; n4++) {
    ((float4*)(Ach + base))[n4] =
        make_float4(A[4 * n4], A[4 * n4 + 1], A[4 * n4 + 2], A[4 * n4 + 3]);
    ((float4*)(Bch + base))[n4] =
        make_float4(S[4 * n4], S[4 * n4 + 1], S[4 * n4 + 2], S[4 * n4 + 3]);
  }
}

__global__ __launch_bounds__(256) void scan_passB(
    const float* __restrict__ Ach, const float* __restrict__ Bch,
    float* __restrict__ S0) {
  const size_t i = (size_t)blockIdx.x * 256 + threadIdx.x;  // 65536 lanes
  float S = 0.f;
  for (int ch = 0; ch < CCH; ch++) {
    const size_t off = (size_t)ch * BDN + i;
    const float a = Ach[off];
    const float bv = Bch[off];
    S0[off] = S;           // exclusive: carry INTO chunk ch
    S = fmaf(S, a, bv);
  }
}

__global__ __launch_bounds__(256) void scan_passC(
    const float* __restrict__ eps, const float* __restrict__ xc,
    const float* __restrict__ xdbl, const float* __restrict__ D_skip,
    const float* __restrict__ S0,
    unsigned short* __restrict__ yHi, unsigned short* __restrict__ yLo) {
  const int d = blockIdx.x * 256 + threadIdx.x;
  const int b = blockIdx.y, ch = blockIdx.z;
  const size_t bl0 = (size_t)b * LL + (size_t)ch * LC;
  const float* ep = eps + bl0 * DSSM + d;
  const float* up = xc + bl0 * DSSM + d;
  const float* kq = xdbl + bl0 * 64;
  unsigned short* ypH = yHi + bl0 * DINNER + d;
  unsigned short* ypL = yLo + bl0 * DINNER + d;
  const float Dv = D_skip[d];
  const size_t base = (size_t)ch * BDN + (((size_t)b * DSSM + d) << 4);
  float S[16];
#pragma unroll
  for (int n4 = 0; n4 < 4; n4++) {
    const float4 v = ((const float4*)(S0 + base))[n4];
    S[4 * n4 + 0] = v.x; S[4 * n4 + 1] = v.y;
    S[4 * n4 + 2] = v.z; S[4 * n4 + 3] = v.w;
  }
#pragma unroll 2
  for (int j = 0; j < LC; j++) {
    const float e = ep[(size_t)j * DSSM];
    const float u = up[(size_t)j * DSSM];
    const float* kj = kq + j * 64 + 32;   // uniform; q at kj[16+n]
#pragma unroll
    for (int n = 0; n < 16; n++) {
      const float k = kj[n];
      const float t0 = e * k;
      const float a = fmaf(-t0, k, 1.f);
      S[n] = fmaf(S[n], a, t0 * u);
    }
    float y0 = 0.f, y1 = 0.f, y2 = 0.f, y3 = 0.f;
#pragma unroll
    for (int n = 0; n < 16; n += 4) {
      y0 = fmaf(S[n + 0], kj[16 + n + 0], y0);
      y1 = fmaf(S[n + 1], kj[16 + n + 1], y1);
      y2 = fmaf(S[n + 2], kj[16 + n + 2], y2);
      y3 = fmaf(S[n + 3], kj[16 + n + 3], y3);
    }
    const float yv = fmaf(Dv, u, (y0 + y1) + (y2 + y3));
    const unsigned short h = f2bf(yv);
    ypH[(size_t)j * DINNER] = h;
    ypL[(size_t)j * DINNER] = f2bf(yv - bf2f(h));
  }
}

// ---------------------------------------------------------------------------
extern "C" void kernel_launch(void* const* d_in, const int* in_sizes, int n_in,
                              void* d_out, int out_size, void* d_ws, size_t ws_size,
                              hipStream_t stream) {
  const float* hidden  = (const float*)d_in[0];
  const float* W_in    = (const float*)d_in[1];
  const float* cxw     = (const float*)d_in[2];
  const float* cxb     = (const float*)d_in[3];
  const float* czw     = (const float*)d_in[4];
  const float* czb     = (const float*)d_in[5];
  const float* W_xproj = (const float*)d_in[6];
  const float* W_dt    = (const float*)d_in[7];
  const float* b_dt    = (const float*)d_in[8];
  const float* D_skip  = (const float*)d_in[9];
  const float* W_out   = (const float*)d_in[10];
  float* out = (float*)d_out;

  const size_t ML  = (size_t)BB * LL;      // 16384
  const size_t MK5 = ML * DSSM;            // 8.4M
  const size_t MN  = ML * DINNER;          // 16.8M
  const size_t WIN = (size_t)DINNER * DMODEL;
  const size_t WOU = (size_t)DMODEL * DINNER;

  unsigned short* hidS  = (unsigned short*)d_ws;   // 2*MK5 shorts
  unsigned short* WinS  = hidS + 2 * MK5;
  unsigned short* WoutS = WinS + 2 * WIN;
  float* xz   = (float*)(WoutS + 2 * WOU);         // MN floats
  float* xc   = xz + MN;                           // MK5 floats
  float* xdbl = xc + MK5;                          // ML*64 floats
  unsigned short* yS = (unsigned short*)(xdbl + ML * 64);  // 2*MN shorts
  float* eps = xz;                                 // alias: xz[0:MK5] dead after conv
  float* S0  = xz + MK5;                           // alias: xz z-half dead after conv
  float* Ach = (float*)hidS;                       // alias: hidS dead after GEMM1
  float* Bch = Ach + (size_t)CCH * BDN;            // exact fit in hidS region

  // 0) fp32 -> split-bf16 planes
  split_kernel<<<2048, 256, 0, stream>>>(hidden, hidS, hidS + MK5, (int)(MK5 / 4));
  split_kernel<<<512, 256, 0, stream>>>(W_in, WinS, WinS + WIN, (int)(WIN / 4));
  split_kernel<<<512, 256, 0, stream>>>(W_out, WoutS, WoutS + WOU, (int)(WOU / 4));

  // 1) xz = hidden @ W_in^T   (MFMA split-bf16; M=16384, N=1024, K=512)
  gemm_mfma_split<<<(16384 / 128) * (1024 / 128), 256, 0, stream>>>(
      hidS, MK5, WinS, WIN, xz, DMODEL, DINNER / 128);

  // 2) depthwise conv + SiLU
  conv_silu_kernel<<<dim3(DINNER / 256, LL, BB), 256, 0, stream>>>(
      xz, cxw, cxb, czw, czb, xc, yS, yS + MN);

  // 3) x_dbl = xc @ W_xproj^T  (fp32; M=16384, N=64, K=512; 1024 blocks)
  gemm_xproj<<<dim3(1024), 256, 0, stream>>>(xc, W_xproj, xdbl);

  // 4) dt -> softplus -> eps  (16 rows/block, 1024 blocks)
  dteps_kernel<<<dim3(1024), 256, 0, stream>>>(xdbl, W_dt, b_dt, eps);

  // 5) chunked scan
  scan_passA<<<dim3(2, BB, CCH), 256, 0, stream>>>(eps, xc, xdbl, Ach, Bch);
  scan_passB<<<dim3(BDN / 256), 256, 0, stream>>>(Ach, Bch, S0);
  scan_passC<<<dim3(2, BB, CCH), 256, 0, stream>>>(
      eps, xc, xdbl, D_skip, S0, yS, yS + MN);

  // 6) out = ycat @ W_out^T  (MFMA split-bf16; M=16384, N=512, K=1024)
  gemm_mfma_split<<<(16384 / 128) * (512 / 128), 256, 0, stream>>>(
      yS, MN, WoutS, WOU, out, DINNER, DMODEL / 128);
}

// Round 7
// 326.127 us; speedup vs baseline: 3.3044x; 1.3130x over previous
//
#include <hip/hip_runtime.h>
#include <hip/hip_bf16.h>
#include <math.h>

#define BB 8
#define LL 2048
#define DMODEL 512
#define DINNER 1024
#define DSSM 512
#define NST 16
#define DTR 32
#define CCH 64            // scan chunks
#define LC (LL / CCH)     // 32 steps per chunk
#define BDN (BB * DSSM * NST)  // 65536 scan lanes
#define CLW 8             // conv l-steps per thread

typedef short short8 __attribute__((ext_vector_type(8)));
typedef float f32x4 __attribute__((ext_vector_type(4)));

// ---- bf16 helpers (RNE, bit-level) ----------------------------------------
__device__ __forceinline__ unsigned short f2bf(float f) {
  unsigned u = __float_as_uint(f);
  u += 0x7FFFu + ((u >> 16) & 1u);
  return (unsigned short)(u >> 16);
}
__device__ __forceinline__ float bf2f(unsigned short s) {
  return __uint_as_float(((unsigned)s) << 16);
}

__device__ __forceinline__ void gload16(const void* g, void* l) {
  __builtin_amdgcn_global_load_lds(
      (const __attribute__((address_space(1))) void*)g,
      (__attribute__((address_space(3))) void*)l, 16, 0, 0);
}

// ---------------------------------------------------------------------------
// bf16 MFMA GEMM: C[M,N] = A[M,K] * W[N,K]^T  (bf16 in, fp32 acc).
// 128x128 tile, BK=64, 256 thr (4 waves, 2x2 of 64x64). LDS rows = 128B
// (64 k-elems), 16B-granule-XOR-swizzled: phys slot s holds granule
// g = s ^ (row&7); applied on gload SOURCE and ds_read ADDR (rule #21).
// 2 MFMAs per (m,n) per K-step (k-low granules 0-3, k-high granules 4-7).
// OUTBF: write bf16 (GEMM1 -> xz) else fp32 (GEMM6 -> out).
// ---------------------------------------------------------------------------
template<bool OUTBF>
__global__ __launch_bounds__(256) void gemm_bf16(
    const unsigned short* __restrict__ Ab,
    const unsigned short* __restrict__ Wb,
    void* __restrict__ Cout, int K, int NBN) {
  __shared__ unsigned short tA[128 * 64];
  __shared__ unsigned short tW[128 * 64];
  const int tid = threadIdx.x;
  const int ln = tid & 63;
  const int wv = tid >> 6;
  const int wr = wv >> 1, wc = wv & 1;
  const int lr = ln & 15, kc = ln >> 4;

  // XCD-chunked bijective swizzle (nwg % 8 == 0), M-major order.
  const int nwg = gridDim.x;
  const int q = nwg >> 3;
  const int bid = blockIdx.x;
  const int wg = (bid & 7) * q + (bid >> 3);
  const int mblk = wg / NBN, nblk = wg % NBN;
  const size_t m0 = (size_t)mblk * 128, n0 = (size_t)nblk * 128;

  f32x4 acc[4][4];
#pragma unroll
  for (int m = 0; m < 4; ++m)
#pragma unroll
    for (int n = 0; n < 4; ++n)
#pragma unroll
      for (int j = 0; j < 4; ++j) acc[m][n][j] = 0.f;

  const int wbase = (tid & 0xC0) << 4;  // wave-uniform byte base

  for (int k0 = 0; k0 < K; k0 += 64) {
#pragma unroll
    for (int it = 0; it < 4; ++it) {
      const int gi = it * 256 + tid;
      const int r = gi >> 3, s = gi & 7, g = s ^ (r & 7);
      const size_t off = (m0 + r) * (size_t)K + (size_t)(k0 + g * 8);
      gload16(Ab + off, (char*)tA + it * 4096 + wbase);
    }
#pragma unroll
    for (int it = 0; it < 4; ++it) {
      const int gi = it * 256 + tid;
      const int r = gi >> 3, s = gi & 7, g = s ^ (r & 7);
      const size_t off = (n0 + r) * (size_t)K + (size_t)(k0 + g * 8);
      gload16(Wb + off, (char*)tW + it * 4096 + wbase);
    }
    __syncthreads();

    short8 alo[4], ahi[4], wlo[4], whi[4];
#pragma unroll
    for (int m = 0; m < 4; ++m) {
      const int ra = wr * 64 + m * 16 + lr;
      const int sl = kc ^ (ra & 7);
      const char* base = (const char*)tA + ra * 128;
      alo[m] = *(const short8*)(base + sl * 16);
      ahi[m] = *(const short8*)(base + (sl ^ 4) * 16);
    }
#pragma unroll
    for (int n = 0; n < 4; ++n) {
      const int rb = wc * 64 + n * 16 + lr;
      const int sl = kc ^ (rb & 7);
      const char* base = (const char*)tW + rb * 128;
      wlo[n] = *(const short8*)(base + sl * 16);
      whi[n] = *(const short8*)(base + (sl ^ 4) * 16);
    }
#pragma unroll
    for (int m = 0; m < 4; ++m)
#pragma unroll
      for (int n = 0; n < 4; ++n) {
        acc[m][n] = __builtin_amdgcn_mfma_f32_16x16x32_bf16(alo[m], wlo[n], acc[m][n], 0, 0, 0);
        acc[m][n] = __builtin_amdgcn_mfma_f32_16x16x32_bf16(ahi[m], whi[n], acc[m][n], 0, 0, 0);
      }
    __syncthreads();
  }

  // C/D layout: col = lane&15, row = (lane>>4)*4 + reg
  const int ldc = NBN * 128;
#pragma unroll
  for (int m = 0; m < 4; ++m) {
    const size_t row0 = m0 + wr * 64 + m * 16 + kc * 4;
#pragma unroll
    for (int n = 0; n < 4; ++n) {
      const size_t col = n0 + wc * 64 + n * 16 + lr;
#pragma unroll
      for (int j = 0; j < 4; ++j) {
        if (OUTBF)
          ((unsigned short*)Cout)[(row0 + j) * (size_t)ldc + col] = f2bf(acc[m][n][j]);
        else
          ((float*)Cout)[(row0 + j) * (size_t)ldc + col] = acc[m][n][j];
      }
    }
  }
}

// ---------------------------------------------------------------------------
// fp32 -> bf16 plane.
// ---------------------------------------------------------------------------
__global__ __launch_bounds__(256) void cvt_kernel(const float* __restrict__ in,
    unsigned short* __restrict__ o, int n4) {
  int i = blockIdx.x * 256 + threadIdx.x;
  const int str = gridDim.x * 256;
  for (; i < n4; i += str) {
    const float4 v = ((const float4*)in)[i];
    ushort4 h;
    h.x = f2bf(v.x); h.y = f2bf(v.y); h.z = f2bf(v.z); h.w = f2bf(v.w);
    ((ushort4*)o)[i] = h;
  }
}

// ---------------------------------------------------------------------------
// x_dbl projection GEMM: C[16384,64] = A[16384,512] * W[64,512]^T  (fp32).
// ---------------------------------------------------------------------------
__global__ __launch_bounds__(256) void gemm_xproj(
    const float* __restrict__ A, const float* __restrict__ W,
    float* __restrict__ C) {
  __shared__ float As[32][16];   // [k][m]
  __shared__ float Ws[32][64];   // [k][n]
  const int t = threadIdx.x;
  const int tn = t & 63, tm = t >> 6;
  const size_t m0 = (size_t)blockIdx.x * 16;
  float acc[4] = {0.f, 0.f, 0.f, 0.f};

  for (int k0 = 0; k0 < 512; k0 += 32) {
    if (t < 128) {
      const int r = t >> 3, c4 = (t & 7) << 2;
      const float4 v = *(const float4*)(A + (m0 + r) * 512 + k0 + c4);
      As[c4 + 0][r] = v.x; As[c4 + 1][r] = v.y;
      As[c4 + 2][r] = v.z; As[c4 + 3][r] = v.w;
    }
#pragma unroll
    for (int rep = 0; rep < 2; rep++) {
      const int f = t + rep * 256;           // 0..511
      const int n = f >> 3, c4 = (f & 7) << 2;
      const float4 v = *(const float4*)(W + n * 512 + k0 + c4);
      Ws[c4 + 0][n] = v.x; Ws[c4 + 1][n] = v.y;
      Ws[c4 + 2][n] = v.z; Ws[c4 + 3][n] = v.w;
    }
    __syncthreads();
#pragma unroll
    for (int k = 0; k < 32; k++) {
      const float4 a4 = *(const float4*)&As[k][tm * 4];
      const float w = Ws[k][tn];
      acc[0] = fmaf(a4.x, w, acc[0]);
      acc[1] = fmaf(a4.y, w, acc[1]);
      acc[2] = fmaf(a4.z, w, acc[2]);
      acc[3] = fmaf(a4.w, w, acc[3]);
    }
    __syncthreads();
  }
#pragma unroll
  for (int i = 0; i < 4; i++)
    C[(m0 + tm * 4 + i) * 64 + tn] = acc[i];
}

// ---------------------------------------------------------------------------
// Depthwise conv + bias + SiLU, register-walk CLW l-steps per thread.
// xz is bf16. x-half -> xc (fp32); z-half -> yB (bf16).
// ---------------------------------------------------------------------------
__global__ __launch_bounds__(256) void conv_silu_kernel(
    const unsigned short* __restrict__ xzB,
    const float* __restrict__ cxw, const float* __restrict__ cxb,
    const float* __restrict__ czw, const float* __restrict__ czb,
    float* __restrict__ xc, unsigned short* __restrict__ yB) {
  const int c = blockIdx.x * 256 + threadIdx.x;  // 0..1023
  const int l0 = blockIdx.y * CLW;
  const int b = blockIdx.z;
  float w0, w1, w2, w3, bias;
  if (c < DSSM) {
    w0 = cxw[c * 4 + 0]; w1 = cxw[c * 4 + 1]; w2 = cxw[c * 4 + 2]; w3 = cxw[c * 4 + 3];
    bias = cxb[c];
  } else {
    const int cz = c - DSSM;
    w0 = czw[cz * 4 + 0]; w1 = czw[cz * 4 + 1]; w2 = czw[cz * 4 + 2]; w3 = czw[cz * 4 + 3];
    bias = czb[cz];
  }
  const unsigned short* base = xzB + ((size_t)b * LL + l0) * DINNER + c;
  float v[CLW + 3];
  v[0] = (l0 > 0) ? bf2f(base[-(int)DINNER]) : 0.f;
#pragma unroll
  for (int i = 0; i <= CLW + 1; i++) {
    const int l = l0 + i;
    v[i + 1] = (l < LL) ? bf2f(base[(size_t)i * DINNER]) : 0.f;
  }
#pragma unroll
  for (int j = 0; j < CLW; j++) {
    float a = bias;
    a = fmaf(v[j + 0], w0, a);
    a = fmaf(v[j + 1], w1, a);
    a = fmaf(v[j + 2], w2, a);
    a = fmaf(v[j + 3], w3, a);
    const float y = a / (1.f + expf(-a));  // SiLU
    const size_t bl = (size_t)b * LL + l0 + j;
    if (c < DSSM)
      xc[bl * DSSM + c] = y;
    else
      yB[bl * DINNER + c] = f2bf(y);
  }
}

// ---------------------------------------------------------------------------
// dteps: 16 (b,l) rows per block, grid 1024. W_dt staged coalesced -> LDS,
// register-persisted (2 d-rows/thread); k2 via 16-lane shfl.
// ---------------------------------------------------------------------------
__global__ __launch_bounds__(256) void dteps_kernel(
    const float* __restrict__ xdbl, const float* __restrict__ W_dt,
    const float* __restrict__ b_dt, float* __restrict__ eps) {
  __shared__ float sW[512 * 36];
  __shared__ float sd[16 * 64];
  __shared__ float sk2[16];
  const int t = threadIdx.x;
  const size_t bl0 = (size_t)blockIdx.x * 16;

#pragma unroll
  for (int it = 0; it < 16; it++) {
    const int i = it * 256 + t;
    const int d = i >> 3, j = i & 7;
    const float4 v = ((const float4*)W_dt)[i];
    *(float4*)&sW[d * 36 + j * 4] = v;
  }
  {
    const float4 v = ((const float4*)(xdbl + bl0 * 64))[t];
    *(float4*)&sd[t * 4] = v;
  }
  __syncthreads();
  {
    const int il = t >> 4, n = t & 15;
    float v = sd[il * 64 + 32 + n];
    v *= v;
    v += __shfl_xor(v, 1); v += __shfl_xor(v, 2);
    v += __shfl_xor(v, 4); v += __shfl_xor(v, 8);
    if (n == 0) sk2[il] = v;
  }
  const int d0 = t, d1 = t + 256;
  float W0[32], W1[32];
#pragma unroll
  for (int j4 = 0; j4 < 8; j4++) {
    *(float4*)&W0[j4 * 4] = *(const float4*)&sW[d0 * 36 + j4 * 4];
    *(float4*)&W1[j4 * 4] = *(const float4*)&sW[d1 * 36 + j4 * 4];
  }
  const float b0 = b_dt[d0], b1 = b_dt[d1];
  __syncthreads();

#pragma unroll
  for (int il = 0; il < 16; il++) {
    float dl[32];
#pragma unroll
    for (int j4 = 0; j4 < 8; j4++)
      *(float4*)&dl[j4 * 4] = *(const float4*)&sd[il * 64 + j4 * 4];
    const float k2 = sk2[il];
    float dt0 = b0, dt1 = b1;
#pragma unroll
    for (int r = 0; r < 32; r++) {
      dt0 = fmaf(W0[r], dl[r], dt0);
      dt1 = fmaf(W1[r], dl[r], dt1);
    }
    const float del0 = (dt0 > 20.f) ? dt0 : log1pf(expf(dt0));
    const float del1 = (dt1 > 20.f) ? dt1 : log1pf(expf(dt1));
    const size_t row = (bl0 + il) * DSSM;
    eps[row + d0] = del0 / (1.f + del0 * k2);
    eps[row + d1] = del1 / (1.f + del1 * k2);
  }
}

// ---------------------------------------------------------------------------
// Chunked scan, thread-per-(b,d): 16 n-states in registers.
// ---------------------------------------------------------------------------
__global__ __launch_bounds__(256) void scan_passA(
    const float* __restrict__ eps, const float* __restrict__ xc,
    const float* __restrict__ xdbl,
    float* __restrict__ Ach, float* __restrict__ Bch) {
  const int d = blockIdx.x * 256 + threadIdx.x;
  const int b = blockIdx.y, ch = blockIdx.z;
  const size_t bl0 = (size_t)b * LL + (size_t)ch * LC;
  const float* ep = eps + bl0 * DSSM + d;
  const float* up = xc + bl0 * DSSM + d;
  const float* kq = xdbl + bl0 * 64;
  float A[16], S[16];
#pragma unroll
  for (int n = 0; n < 16; n++) { A[n] = 1.f; S[n] = 0.f; }
#pragma unroll 2
  for (int j = 0; j < LC; j++) {
    const float e = ep[(size_t)j * DSSM];
    const float u = up[(size_t)j * DSSM];
    const float* kj = kq + j * 64 + 32;   // uniform address
#pragma unroll
    for (int n = 0; n < 16; n++) {
      const float k = kj[n];
      const float t0 = e * k;
      const float a = fmaf(-t0, k, 1.f);
      A[n] *= a;
      S[n] = fmaf(S[n], a, t0 * u);
    }
  }
  const size_t base = (size_t)ch * BDN + (((size_t)b * DSSM + d) << 4);
#pragma unroll
  for (int n4 = 0; n4 < 4; n4++) {
    ((float4*)(Ach + base))[n4] =
        make_float4(A[4 * n4], A[4 * n4 + 1], A[4 * n4 + 2], A[4 * n4 + 3]);
    ((float4*)(Bch + base))[n4] =
        make_float4(S[4 * n4], S[4 * n4 + 1], S[4 * n4 + 2], S[4 * n4 + 3]);
  }
}

__global__ __launch_bounds__(256) void scan_passB(
    const float* __restrict__ Ach, const float* __restrict__ Bch,
    float* __restrict__ S0) {
  const size_t i = (size_t)blockIdx.x * 256 + threadIdx.x;  // 65536 lanes
  float S = 0.f;
  for (int ch = 0; ch < CCH; ch++) {
    const size_t off = (size_t)ch * BDN + i;
    const float a = Ach[off];
    const float bv = Bch[off];
    S0[off] = S;           // exclusive: carry INTO chunk ch
    S = fmaf(S, a, bv);
  }
}

__global__ __launch_bounds__(256) void scan_passC(
    const float* __restrict__ eps, const float* __restrict__ xc,
    const float* __restrict__ xdbl, const float* __restrict__ D_skip,
    const float* __restrict__ S0, unsigned short* __restrict__ yB) {
  const int d = blockIdx.x * 256 + threadIdx.x;
  const int b = blockIdx.y, ch = blockIdx.z;
  const size_t bl0 = (size_t)b * LL + (size_t)ch * LC;
  const float* ep = eps + bl0 * DSSM + d;
  const float* up = xc + bl0 * DSSM + d;
  const float* kq = xdbl + bl0 * 64;
  unsigned short* yp = yB + bl0 * DINNER + d;
  const float Dv = D_skip[d];
  const size_t base = (size_t)ch * BDN + (((size_t)b * DSSM + d) << 4);
  float S[16];
#pragma unroll
  for (int n4 = 0; n4 < 4; n4++) {
    const float4 v = ((const float4*)(S0 + base))[n4];
    S[4 * n4 + 0] = v.x; S[4 * n4 + 1] = v.y;
    S[4 * n4 + 2] = v.z; S[4 * n4 + 3] = v.w;
  }
#pragma unroll 2
  for (int j = 0; j < LC; j++) {
    const float e = ep[(size_t)j * DSSM];
    const float u = up[(size_t)j * DSSM];
    const float* kj = kq + j * 64 + 32;   // uniform; q at kj[16+n]
#pragma unroll
    for (int n = 0; n < 16; n++) {
      const float k = kj[n];
      const float t0 = e * k;
      const float a = fmaf(-t0, k, 1.f);
      S[n] = fmaf(S[n], a, t0 * u);
    }
    float y0 = 0.f, y1 = 0.f, y2 = 0.f, y3 = 0.f;
#pragma unroll
    for (int n = 0; n < 16; n += 4) {
      y0 = fmaf(S[n + 0], kj[16 + n + 0], y0);
      y1 = fmaf(S[n + 1], kj[16 + n + 1], y1);
      y2 = fmaf(S[n + 2], kj[16 + n + 2], y2);
      y3 = fmaf(S[n + 3], kj[16 + n + 3], y3);
    }
    const float yv = fmaf(Dv, u, (y0 + y1) + (y2 + y3));
    yp[(size_t)j * DINNER] = f2bf(yv);
  }
}

// ---------------------------------------------------------------------------
extern "C" void kernel_launch(void* const* d_in, const int* in_sizes, int n_in,
                              void* d_out, int out_size, void* d_ws, size_t ws_size,
                              hipStream_t stream) {
  const float* hidden  = (const float*)d_in[0];
  const float* W_in    = (const float*)d_in[1];
  const float* cxw     = (const float*)d_in[2];
  const float* cxb     = (const float*)d_in[3];
  const float* czw     = (const float*)d_in[4];
  const float* czb     = (const float*)d_in[5];
  const float* W_xproj = (const float*)d_in[6];
  const float* W_dt    = (const float*)d_in[7];
  const float* b_dt    = (const float*)d_in[8];
  const float* D_skip  = (const float*)d_in[9];
  const float* W_out   = (const float*)d_in[10];
  float* out = (float*)d_out;

  const size_t ML  = (size_t)BB * LL;      // 16384
  const size_t MK5 = ML * DSSM;            // 8.4M
  const size_t MN  = ML * DINNER;          // 16.8M
  const size_t WIN = (size_t)DINNER * DMODEL;
  const size_t WOU = (size_t)DMODEL * DINNER;
  const size_t CB  = (size_t)CCH * BDN;    // 4.2M

  // no aliasing: total ~207.6 MB (within known-good ws footprint)
  unsigned short* hidB  = (unsigned short*)d_ws;       // MK5
  unsigned short* WinB  = hidB + MK5;                  // WIN
  unsigned short* WoutB = WinB + WIN;                  // WOU
  unsigned short* xzB   = WoutB + WOU;                 // MN
  unsigned short* yB    = xzB + MN;                    // MN
  float* xc   = (float*)(yB + MN);                     // MK5
  float* xdbl = xc + MK5;                              // ML*64
  float* eps  = xdbl + ML * 64;                        // MK5
  float* Ach  = eps + MK5;                             // CB
  float* Bch  = Ach + CB;                              // CB
  float* S0   = Bch + CB;                              // CB

  // 0) fp32 -> bf16 planes
  cvt_kernel<<<2048, 256, 0, stream>>>(hidden, hidB, (int)(MK5 / 4));
  cvt_kernel<<<512, 256, 0, stream>>>(W_in, WinB, (int)(WIN / 4));
  cvt_kernel<<<512, 256, 0, stream>>>(W_out, WoutB, (int)(WOU / 4));

  // 1) xz = hidden @ W_in^T   (bf16 MFMA; M=16384, N=1024, K=512; bf16 out)
  gemm_bf16<true><<<(16384 / 128) * (1024 / 128), 256, 0, stream>>>(
      hidB, WinB, xzB, DMODEL, DINNER / 128);

  // 2) depthwise conv + SiLU  (bf16 in; xc fp32 + yB z-half bf16)
  conv_silu_kernel<<<dim3(DINNER / 256, LL / CLW, BB), 256, 0, stream>>>(
      xzB, cxw, cxb, czw, czb, xc, yB);

  // 3) x_dbl = xc @ W_xproj^T  (fp32; 1024 blocks)
  gemm_xproj<<<dim3(1024), 256, 0, stream>>>(xc, W_xproj, xdbl);

  // 4) dt -> softplus -> eps
  dteps_kernel<<<dim3(1024), 256, 0, stream>>>(xdbl, W_dt, b_dt, eps);

  // 5) chunked scan -> y into yB channels 0..511
  scan_passA<<<dim3(2, BB, CCH), 256, 0, stream>>>(eps, xc, xdbl, Ach, Bch);
  scan_passB<<<dim3(BDN / 256), 256, 0, stream>>>(Ach, Bch, S0);
  scan_passC<<<dim3(2, BB, CCH), 256, 0, stream>>>(
      eps, xc, xdbl, D_skip, S0, yB);

  // 6) out = ycat @ W_out^T  (bf16 MFMA; M=16384, N=512, K=1024; fp32 out)
  gemm_bf16<false><<<(16384 / 128) * (512 / 128), 256, 0, stream>>>(
      yB, WoutB, out, DINNER, DMODEL / 128);
}

// Round 8
// 286.781 us; speedup vs baseline: 3.7578x; 1.1372x over previous
//
#include <hip/hip_runtime.h>
#include <hip/hip_bf16.h>
#include <math.h>

#define BB 8
#define LL 2048
#define DMODEL 512
#define DINNER 1024
#define DSSM 512
#define NST 16
#define DTR 32
#define NXD 640           // xdbl2 row stride (512 dt + 16 k + 16 q + 96 pad)
#define CCH 64            // scan chunks
#define LC (LL / CCH)     // 32 steps per chunk
#define BDN (BB * DSSM * NST)  // 65536 scan lanes
#define CLW 8             // conv l-steps per thread

typedef short short8 __attribute__((ext_vector_type(8)));
typedef float f32x4 __attribute__((ext_vector_type(4)));

// ---- bf16 helpers (RNE, bit-level) ----------------------------------------
__device__ __forceinline__ unsigned short f2bf(float f) {
  unsigned u = __float_as_uint(f);
  u += 0x7FFFu + ((u >> 16) & 1u);
  return (unsigned short)(u >> 16);
}
__device__ __forceinline__ float bf2f(unsigned short s) {
  return __uint_as_float(((unsigned)s) << 16);
}

__device__ __forceinline__ void gload16(const void* g, void* l) {
  __builtin_amdgcn_global_load_lds(
      (const __attribute__((address_space(1))) void*)g,
      (__attribute__((address_space(3))) void*)l, 16, 0, 0);
}

// ---------------------------------------------------------------------------
// bf16 MFMA GEMM: C[M,N] = A[M,K] * W[N,K]^T  (bf16 in, fp32 acc).
// 128x128 tile, BK=64, 256 thr (4 waves, 2x2 of 64x64). LDS rows = 128B
// (64 k-elems), 16B-granule-XOR-swizzled (source-side + read-side).
// OUTBF: write bf16 else fp32.
// ---------------------------------------------------------------------------
template<bool OUTBF>
__global__ __launch_bounds__(256) void gemm_bf16(
    const unsigned short* __restrict__ Ab,
    const unsigned short* __restrict__ Wb,
    void* __restrict__ Cout, int K, int NBN) {
  __shared__ unsigned short tA[128 * 64];
  __shared__ unsigned short tW[128 * 64];
  const int tid = threadIdx.x;
  const int ln = tid & 63;
  const int wv = tid >> 6;
  const int wr = wv >> 1, wc = wv & 1;
  const int lr = ln & 15, kc = ln >> 4;

  // XCD-chunked bijective swizzle (nwg % 8 == 0), M-major order.
  const int nwg = gridDim.x;
  const int q = nwg >> 3;
  const int bid = blockIdx.x;
  const int wg = (bid & 7) * q + (bid >> 3);
  const int mblk = wg / NBN, nblk = wg % NBN;
  const size_t m0 = (size_t)mblk * 128, n0 = (size_t)nblk * 128;

  f32x4 acc[4][4];
#pragma unroll
  for (int m = 0; m < 4; ++m)
#pragma unroll
    for (int n = 0; n < 4; ++n)
#pragma unroll
      for (int j = 0; j < 4; ++j) acc[m][n][j] = 0.f;

  const int wbase = (tid & 0xC0) << 4;  // wave-uniform byte base

  for (int k0 = 0; k0 < K; k0 += 64) {
#pragma unroll
    for (int it = 0; it < 4; ++it) {
      const int gi = it * 256 + tid;
      const int r = gi >> 3, s = gi & 7, g = s ^ (r & 7);
      const size_t off = (m0 + r) * (size_t)K + (size_t)(k0 + g * 8);
      gload16(Ab + off, (char*)tA + it * 4096 + wbase);
    }
#pragma unroll
    for (int it = 0; it < 4; ++it) {
      const int gi = it * 256 + tid;
      const int r = gi >> 3, s = gi & 7, g = s ^ (r & 7);
      const size_t off = (n0 + r) * (size_t)K + (size_t)(k0 + g * 8);
      gload16(Wb + off, (char*)tW + it * 4096 + wbase);
    }
    __syncthreads();

    short8 alo[4], ahi[4], wlo[4], whi[4];
#pragma unroll
    for (int m = 0; m < 4; ++m) {
      const int ra = wr * 64 + m * 16 + lr;
      const int sl = kc ^ (ra & 7);
      const char* base = (const char*)tA + ra * 128;
      alo[m] = *(const short8*)(base + sl * 16);
      ahi[m] = *(const short8*)(base + (sl ^ 4) * 16);
    }
#pragma unroll
    for (int n = 0; n < 4; ++n) {
      const int rb = wc * 64 + n * 16 + lr;
      const int sl = kc ^ (rb & 7);
      const char* base = (const char*)tW + rb * 128;
      wlo[n] = *(const short8*)(base + sl * 16);
      whi[n] = *(const short8*)(base + (sl ^ 4) * 16);
    }
#pragma unroll
    for (int m = 0; m < 4; ++m)
#pragma unroll
      for (int n = 0; n < 4; ++n) {
        acc[m][n] = __builtin_amdgcn_mfma_f32_16x16x32_bf16(alo[m], wlo[n], acc[m][n], 0, 0, 0);
        acc[m][n] = __builtin_amdgcn_mfma_f32_16x16x32_bf16(ahi[m], whi[n], acc[m][n], 0, 0, 0);
      }
    __syncthreads();
  }

  // C/D layout: col = lane&15, row = (lane>>4)*4 + reg
  const int ldc = NBN * 128;
#pragma unroll
  for (int m = 0; m < 4; ++m) {
    const size_t row0 = m0 + wr * 64 + m * 16 + kc * 4;
#pragma unroll
    for (int n = 0; n < 4; ++n) {
      const size_t col = n0 + wc * 64 + n * 16 + lr;
#pragma unroll
      for (int j = 0; j < 4; ++j) {
        if (OUTBF)
          ((unsigned short*)Cout)[(row0 + j) * (size_t)ldc + col] = f2bf(acc[m][n][j]);
        else
          ((float*)Cout)[(row0 + j) * (size_t)ldc + col] = acc[m][n][j];
      }
    }
  }
}

// ---------------------------------------------------------------------------
// fp32 -> bf16 plane.
// ---------------------------------------------------------------------------
__global__ __launch_bounds__(256) void cvt_kernel(const float* __restrict__ in,
    unsigned short* __restrict__ o, int n4) {
  int i = blockIdx.x * 256 + threadIdx.x;
  const int str = gridDim.x * 256;
  for (; i < n4; i += str) {
    const float4 v = ((const float4*)in)[i];
    ushort4 h;
    h.x = f2bf(v.x); h.y = f2bf(v.y); h.z = f2bf(v.z); h.w = f2bf(v.w);
    ((ushort4*)o)[i] = h;
  }
}

// ---------------------------------------------------------------------------
// Wcat[640][512] bf16: rows 0..511 = W_dt @ W_xproj[:32]  (dt fusion),
// rows 512..543 = W_xproj[32:64] (k,q), rows 544..639 = 0 (tile pad).
// ---------------------------------------------------------------------------
__global__ __launch_bounds__(256) void weff_kernel(
    const float* __restrict__ W_dt, const float* __restrict__ W_xproj,
    unsigned short* __restrict__ WcatB) {
  const int c = blockIdx.x * 256 + threadIdx.x;   // 0..511
  const int r0 = blockIdx.y;                      // 0..639
  float v;
  if (r0 < 512) {
    float acc = 0.f;
#pragma unroll
    for (int r = 0; r < 32; r++)
      acc = fmaf(W_dt[r0 * 32 + r], W_xproj[r * 512 + c], acc);
    v = acc;
  } else if (r0 < 544) {
    v = W_xproj[(r0 - 480) * 512 + c];   // row 32 + (r0-512)
  } else {
    v = 0.f;
  }
  WcatB[(size_t)r0 * 512 + c] = f2bf(v);
}

// ---------------------------------------------------------------------------
// Depthwise conv + bias + SiLU, register-walk CLW l-steps per thread.
// xz bf16 in. x-half -> xcB (bf16); z-half -> yB (bf16).
// ---------------------------------------------------------------------------
__global__ __launch_bounds__(256) void conv_silu_kernel(
    const unsigned short* __restrict__ xzB,
    const float* __restrict__ cxw, const float* __restrict__ cxb,
    const float* __restrict__ czw, const float* __restrict__ czb,
    unsigned short* __restrict__ xcB, unsigned short* __restrict__ yB) {
  const int c = blockIdx.x * 256 + threadIdx.x;  // 0..1023
  const int l0 = blockIdx.y * CLW;
  const int b = blockIdx.z;
  float w0, w1, w2, w3, bias;
  if (c < DSSM) {
    w0 = cxw[c * 4 + 0]; w1 = cxw[c * 4 + 1]; w2 = cxw[c * 4 + 2]; w3 = cxw[c * 4 + 3];
    bias = cxb[c];
  } else {
    const int cz = c - DSSM;
    w0 = czw[cz * 4 + 0]; w1 = czw[cz * 4 + 1]; w2 = czw[cz * 4 + 2]; w3 = czw[cz * 4 + 3];
    bias = czb[cz];
  }
  const unsigned short* base = xzB + ((size_t)b * LL + l0) * DINNER + c;
  float v[CLW + 3];
  v[0] = (l0 > 0) ? bf2f(base[-(int)DINNER]) : 0.f;
#pragma unroll
  for (int i = 0; i <= CLW + 1; i++) {
    const int l = l0 + i;
    v[i + 1] = (l < LL) ? bf2f(base[(size_t)i * DINNER]) : 0.f;
  }
#pragma unroll
  for (int j = 0; j < CLW; j++) {
    float a = bias;
    a = fmaf(v[j + 0], w0, a);
    a = fmaf(v[j + 1], w1, a);
    a = fmaf(v[j + 2], w2, a);
    a = fmaf(v[j + 3], w3, a);
    const float y = a / (1.f + expf(-a));  // SiLU
    const size_t bl = (size_t)b * LL + l0 + j;
    if (c < DSSM)
      xcB[bl * DSSM + c] = f2bf(y);
    else
      yB[bl * DINNER + c] = f2bf(y);
  }
}

// ---------------------------------------------------------------------------
// eps from fused dt: delta = softplus(dt + b_dt); k2 = sum k^2 (uniform);
// eps = delta/(1+delta*k2). One block per (row, half).
// ---------------------------------------------------------------------------
__global__ __launch_bounds__(256) void dteps2_kernel(
    const float* __restrict__ xdbl2, const float* __restrict__ b_dt,
    float* __restrict__ eps) {
  const int half = blockIdx.x;          // 0..1
  const size_t row = blockIdx.y;        // 0..ML-1
  const int d = half * 256 + threadIdx.x;
  const float* rp = xdbl2 + row * NXD;
  float k2 = 0.f;
#pragma unroll
  for (int n = 0; n < 16; n++) { const float kv = rp[512 + n]; k2 = fmaf(kv, kv, k2); }
  const float dt = rp[d] + b_dt[d];
  const float delta = (dt > 20.f) ? dt : log1pf(expf(dt));
  eps[row * DSSM + d] = delta / (1.f + delta * k2);
}

// ---------------------------------------------------------------------------
// Chunked scan, thread-per-(b,d): 16 n-states in registers.
// u from bf16 xcB; k,q from xdbl2 (stride NXD, k at +512, q at +528).
// ---------------------------------------------------------------------------
__global__ __launch_bounds__(256) void scan_passA(
    const float* __restrict__ eps, const unsigned short* __restrict__ xcB,
    const float* __restrict__ xdbl2,
    float* __restrict__ Ach, float* __restrict__ Bch) {
  const int d = blockIdx.x * 256 + threadIdx.x;
  const int b = blockIdx.y, ch = blockIdx.z;
  const size_t bl0 = (size_t)b * LL + (size_t)ch * LC;
  const float* ep = eps + bl0 * DSSM + d;
  const unsigned short* up = xcB + bl0 * DSSM + d;
  const float* kq = xdbl2 + bl0 * NXD + 512;
  float A[16], S[16];
#pragma unroll
  for (int n = 0; n < 16; n++) { A[n] = 1.f; S[n] = 0.f; }
#pragma unroll 2
  for (int j = 0; j < LC; j++) {
    const float e = ep[(size_t)j * DSSM];
    const float u = bf2f(up[(size_t)j * DSSM]);
    const float* kj = kq + j * NXD;       // uniform address
#pragma unroll
    for (int n = 0; n < 16; n++) {
      const float k = kj[n];
      const float t0 = e * k;
      const float a = fmaf(-t0, k, 1.f);
      A[n] *= a;
      S[n] = fmaf(S[n], a, t0 * u);
    }
  }
  const size_t base = (size_t)ch * BDN + (((size_t)b * DSSM + d) << 4);
#pragma unroll
  for (int n4 = 0; n4 < 4; n4++) {
    ((float4*)(Ach + base))[n4] =
        make_float4(A[4 * n4], A[4 * n4 + 1], A[4 * n4 + 2], A[4 * n4 + 3]);
    ((float4*)(Bch + base))[n4] =
        make_float4(S[4 * n4], S[4 * n4 + 1], S[4 * n4 + 2], S[4 * n4 + 3]);
  }
}

__global__ __launch_bounds__(256) void scan_passB(
    const float* __restrict__ Ach, const float* __restrict__ Bch,
    float* __restrict__ S0) {
  const size_t i = (size_t)blockIdx.x * 256 + threadIdx.x;  // 65536 lanes
  float S = 0.f;
  for (int ch = 0; ch < CCH; ch++) {
    const size_t off = (size_t)ch * BDN + i;
    const float a = Ach[off];
    const float bv = Bch[off];
    S0[off] = S;           // exclusive: carry INTO chunk ch
    S = fmaf(S, a, bv);
  }
}

__global__ __launch_bounds__(256) void scan_passC(
    const float* __restrict__ eps, const unsigned short* __restrict__ xcB,
    const float* __restrict__ xdbl2, const float* __restrict__ D_skip,
    const float* __restrict__ S0, unsigned short* __restrict__ yB) {
  const int d = blockIdx.x * 256 + threadIdx.x;
  const int b = blockIdx.y, ch = blockIdx.z;
  const size_t bl0 = (size_t)b * LL + (size_t)ch * LC;
  const float* ep = eps + bl0 * DSSM + d;
  const unsigned short* up = xcB + bl0 * DSSM + d;
  const float* kq = xdbl2 + bl0 * NXD + 512;
  unsigned short* yp = yB + bl0 * DINNER + d;
  const float Dv = D_skip[d];
  const size_t base = (size_t)ch * BDN + (((size_t)b * DSSM + d) << 4);
  float S[16];
#pragma unroll
  for (int n4 = 0; n4 < 4; n4++) {
    const float4 v = ((const float4*)(S0 + base))[n4];
    S[4 * n4 + 0] = v.x; S[4 * n4 + 1] = v.y;
    S[4 * n4 + 2] = v.z; S[4 * n4 + 3] = v.w;
  }
#pragma unroll 2
  for (int j = 0; j < LC; j++) {
    const float e = ep[(size_t)j * DSSM];
    const float u = bf2f(up[(size_t)j * DSSM]);
    const float* kj = kq + j * NXD;       // uniform; q at kj[16+n]
#pragma unroll
    for (int n = 0; n < 16; n++) {
      const float k = kj[n];
      const float t0 = e * k;
      const float a = fmaf(-t0, k, 1.f);
      S[n] = fmaf(S[n], a, t0 * u);
    }
    float y0 = 0.f, y1 = 0.f, y2 = 0.f, y3 = 0.f;
#pragma unroll
    for (int n = 0; n < 16; n += 4) {
      y0 = fmaf(S[n + 0], kj[16 + n + 0], y0);
      y1 = fmaf(S[n + 1], kj[16 + n + 1], y1);
      y2 = fmaf(S[n + 2], kj[16 + n + 2], y2);
      y3 = fmaf(S[n + 3], kj[16 + n + 3], y3);
    }
    const float yv = fmaf(Dv, u, (y0 + y1) + (y2 + y3));
    yp[(size_t)j * DINNER] = f2bf(yv);
  }
}

// ---------------------------------------------------------------------------
extern "C" void kernel_launch(void* const* d_in, const int* in_sizes, int n_in,
                              void* d_out, int out_size, void* d_ws, size_t ws_size,
                              hipStream_t stream) {
  const float* hidden  = (const float*)d_in[0];
  const float* W_in    = (const float*)d_in[1];
  const float* cxw     = (const float*)d_in[2];
  const float* cxb     = (const float*)d_in[3];
  const float* czw     = (const float*)d_in[4];
  const float* czb     = (const float*)d_in[5];
  const float* W_xproj = (const float*)d_in[6];
  const float* W_dt    = (const float*)d_in[7];
  const float* b_dt    = (const float*)d_in[8];
  const float* D_skip  = (const float*)d_in[9];
  const float* W_out   = (const float*)d_in[10];
  float* out = (float*)d_out;

  const size_t ML  = (size_t)BB * LL;      // 16384
  const size_t MK5 = ML * DSSM;            // 8.4M
  const size_t MN  = ML * DINNER;          // 16.8M
  const size_t WIN = (size_t)DINNER * DMODEL;
  const size_t WOU = (size_t)DMODEL * DINNER;
  const size_t WCT = (size_t)NXD * DMODEL; // 640*512
  const size_t CB  = (size_t)CCH * BDN;    // 4.19M floats

  // layout (~179 MB): hidB+xzB at the end so Ach/Bch/S0 alias them exactly.
  unsigned short* WinB  = (unsigned short*)d_ws;       // WIN
  unsigned short* WoutB = WinB + WIN;                  // WOU
  unsigned short* WcatB = WoutB + WOU;                 // WCT
  unsigned short* xcB   = WcatB + WCT;                 // MK5
  unsigned short* yB    = xcB + MK5;                   // MN
  float* xdbl2 = (float*)(yB + MN);                    // ML*NXD
  float* eps   = xdbl2 + ML * NXD;                     // MK5
  unsigned short* hidB = (unsigned short*)(eps + MK5); // MK5
  unsigned short* xzB  = hidB + MK5;                   // MN
  float* Ach = (float*)hidB;     // 3*CB floats == hidB+xzB bytes exactly
  float* Bch = Ach + CB;
  float* S0  = Bch + CB;

  // 0) fp32 -> bf16 planes; fused weight build
  cvt_kernel<<<2048, 256, 0, stream>>>(hidden, hidB, (int)(MK5 / 4));
  cvt_kernel<<<512, 256, 0, stream>>>(W_in, WinB, (int)(WIN / 4));
  cvt_kernel<<<512, 256, 0, stream>>>(W_out, WoutB, (int)(WOU / 4));
  weff_kernel<<<dim3(2, NXD), 256, 0, stream>>>(W_dt, W_xproj, WcatB);

  // 1) xz = hidden @ W_in^T   (bf16 MFMA; M=16384, N=1024, K=512; bf16 out)
  gemm_bf16<true><<<(16384 / 128) * (1024 / 128), 256, 0, stream>>>(
      hidB, WinB, xzB, DMODEL, DINNER / 128);

  // 2) depthwise conv + SiLU  (bf16 in; xcB + yB z-half bf16)
  conv_silu_kernel<<<dim3(DINNER / 256, LL / CLW, BB), 256, 0, stream>>>(
      xzB, cxw, cxb, czw, czb, xcB, yB);

  // 3) xdbl2 = xc @ Wcat^T  (bf16 MFMA; M=16384, N=640, K=512; fp32 out)
  //    cols 0..511 = dt, 512..527 = k, 528..543 = q
  gemm_bf16<false><<<(16384 / 128) * (NXD / 128), 256, 0, stream>>>(
      xcB, WcatB, xdbl2, DMODEL, NXD / 128);

  // 4) eps = softplus(dt+b_dt) / (1 + . * k2)
  dteps2_kernel<<<dim3(2, (unsigned)ML), 256, 0, stream>>>(xdbl2, b_dt, eps);

  // 5) chunked scan -> y into yB channels 0..511
  scan_passA<<<dim3(2, BB, CCH), 256, 0, stream>>>(eps, xcB, xdbl2, Ach, Bch);
  scan_passB<<<dim3(BDN / 256), 256, 0, stream>>>(Ach, Bch, S0);
  scan_passC<<<dim3(2, BB, CCH), 256, 0, stream>>>(
      eps, xcB, xdbl2, D_skip, S0, yB);

  // 6) out = ycat @ W_out^T  (bf16 MFMA; M=16384, N=512, K=1024; fp32 out)
  gemm_bf16<false><<<(16384 / 128) * (512 / 128), 256, 0, stream>>>(
      yB, WoutB, out, DINNER, DMODEL / 128);
}